// Round 3
// baseline (4778.268 us; speedup 1.0000x reference)
//
#include <hip/hip_runtime.h>

typedef unsigned short u16;
typedef unsigned int   u32;
typedef short   short8  __attribute__((ext_vector_type(8)));
typedef float   floatx4 __attribute__((ext_vector_type(4)));

#define NTOK 8192
#define SEQ  512
#define NLAYER 6

// ---- workspace layout (bytes) ----
#define OFF_WT   ((size_t)0)          // transposed weights (bf16), 19,005,440 u16
#define OFF_HF   ((size_t)38010880)   // h fp32   [8192][512]
#define OFF_HB   ((size_t)54788096)   // h bf16   [8192][512]
#define OFF_QKV  ((size_t)63176704)   // qkv bf16 [8192][1536]
#define OFF_CTX  ((size_t)88342528)   // ctx bf16 [8192][512]
#define OFF_GOUT ((size_t)96731136)   // gemm out fp32 [8192][512]
#define OFF_FF   ((size_t)113508352)  // ff bf16  [8192][2048]
#define OFF_HD1  ((size_t)147062784)  // head1 bf16 [8192][256]
// total ~151.3 MB

#define LSTRIDE 3145728   // wT elems per layer: [QT;KT;VT](1536x512), WoT, w1T(2048x512), w2T(512x2048)
#define P1T_OFF 18874368  // p1T [256][512]

__device__ __forceinline__ float b2f(u16 v) { return __uint_as_float(((u32)v) << 16); }
__device__ __forceinline__ float lo16(u32 v) { return __uint_as_float(v << 16); }
__device__ __forceinline__ float hi16(u32 v) { return __uint_as_float(v & 0xffff0000u); }
__device__ __forceinline__ u16 f2b(float f) {
  u32 x = __float_as_uint(f);
  return (u16)((x + 0x7fffu + ((x >> 16) & 1u)) >> 16);
}
__device__ __forceinline__ u32 pack2(float a, float b) {
  return (u32)f2b(a) | ((u32)f2b(b) << 16);
}

typedef __attribute__((address_space(1))) void* gas_t;
typedef __attribute__((address_space(3))) void* las_t;

// ---------------------------------------------------------------------------
// Transpose all f32 weight matrices into wT (bf16 [N][K] for gemm_bt).
// ---------------------------------------------------------------------------
__global__ __launch_bounds__(256) void transpose_all(
    const float* __restrict__ Wq, const float* __restrict__ Wk,
    const float* __restrict__ Wv, const float* __restrict__ Wo,
    const float* __restrict__ w1, const float* __restrict__ w2,
    const float* __restrict__ p1, u16* __restrict__ wT)
{
  __shared__ u16 tile[64][65];
  const int tb = blockIdx.x;
  const float* src; u16* dst; int R, C, tidx;
  if (tb < 4608) {
    const int l = tb / 768, r = tb % 768;
    const size_t lofs = (size_t)l * LSTRIDE;
    if (r < 256) {
      const int m = r >> 6; tidx = r & 63; R = 512; C = 512;
      const float* bases[4] = {Wq, Wk, Wv, Wo};
      src = bases[m] + (size_t)l * 262144;
      dst = wT + lofs + (size_t)m * 262144;
    } else if (r < 512) {
      tidx = r - 256; R = 512; C = 2048;
      src = w1 + (size_t)l * 1048576; dst = wT + lofs + 1048576;
    } else {
      tidx = r - 512; R = 2048; C = 512;
      src = w2 + (size_t)l * 1048576; dst = wT + lofs + 2097152;
    }
  } else {
    tidx = tb - 4608; R = 512; C = 256;
    src = p1; dst = wT + P1T_OFF;
  }
  const int tcn = C >> 6;
  const int tr = tidx / tcn, tc = tidx % tcn;
  const int th = threadIdx.x;
  {
    const int lr = th >> 2, cg = (th & 3) * 16;
    const float* sp = src + (size_t)(tr*64 + lr) * C + tc*64 + cg;
    float4 f0 = *(const float4*)(sp);
    float4 f1 = *(const float4*)(sp + 4);
    float4 f2 = *(const float4*)(sp + 8);
    float4 f3 = *(const float4*)(sp + 12);
    u16* tp = &tile[lr][cg];
    tp[0]=f2b(f0.x); tp[1]=f2b(f0.y); tp[2]=f2b(f0.z); tp[3]=f2b(f0.w);
    tp[4]=f2b(f1.x); tp[5]=f2b(f1.y); tp[6]=f2b(f1.z); tp[7]=f2b(f1.w);
    tp[8]=f2b(f2.x); tp[9]=f2b(f2.y); tp[10]=f2b(f2.z); tp[11]=f2b(f2.w);
    tp[12]=f2b(f3.x); tp[13]=f2b(f3.y); tp[14]=f2b(f3.z); tp[15]=f2b(f3.w);
  }
  __syncthreads();
  {
    const int oc = th >> 2, rg = (th & 3) * 16;
    u32 wds[8];
    #pragma unroll
    for (int i = 0; i < 8; ++i)
      wds[i] = (u32)tile[rg + 2*i][oc] | ((u32)tile[rg + 2*i + 1][oc] << 16);
    u16* dp = dst + (size_t)(tc*64 + oc) * R + tr*64 + rg;
    uint4 o0; o0.x=wds[0]; o0.y=wds[1]; o0.z=wds[2]; o0.w=wds[3];
    uint4 o1; o1.x=wds[4]; o1.y=wds[5]; o1.z=wds[6]; o1.w=wds[7];
    *(uint4*)dp = o0;
    *(uint4*)(dp + 8) = o1;
  }
}

// ---------------------------------------------------------------------------
// h = x @ in_w + in_b + sinusoidal_pe   (K=50, exact f32)
// ---------------------------------------------------------------------------
__global__ __launch_bounds__(128) void input_proj(
    const float* __restrict__ x, const float* __restrict__ w, const float* __restrict__ ib,
    float* __restrict__ hf, u16* __restrict__ hb)
{
  const int row = blockIdx.x, t = threadIdx.x;
  const int s = row & (SEQ - 1);
  __shared__ float xs[50];
  if (t < 50) xs[t] = x[row*50 + t];
  __syncthreads();
  #pragma unroll
  for (int rep = 0; rep < 4; ++rep) {
    const int d = rep*128 + t;
    float acc = ib[d];
    #pragma unroll
    for (int i = 0; i < 50; ++i) acc += xs[i] * w[i*512 + d];
    const int ii = d >> 1;
    const float dv = __expf((float)(2*ii) * -0.017988946f); // -ln(10000)/512
    const float ang = (float)s * dv;
    const float pe = (d & 1) ? cosf(ang) : sinf(ang);
    const float v = acc + pe;
    hf[(size_t)row*512 + d] = v;
    hb[(size_t)row*512 + d] = f2b(v);
  }
}

// ---------------------------------------------------------------------------
// C[M][N] = A[M][K](bf16) @ Bt[N][K]^T (+bias f32)(relu?) -> f32 or bf16
// m97-style: 128x128x32 tile, global_load_lds(16B), mfma 16x16x32 bf16
// ---------------------------------------------------------------------------
__global__ __launch_bounds__(256) void gemm_bt(
    const u16* __restrict__ A, const u16* __restrict__ Bt,
    const float* __restrict__ bias, float* __restrict__ outF, u16* __restrict__ outB,
    const int M, const int N, const int K, const int flags)
{
  __shared__ __align__(16) u16 As[128*32];
  __shared__ __align__(16) u16 Bs[128*32];
  const int nb = N >> 7;
  const int bm = blockIdx.x / nb, bn = blockIdx.x % nb;
  const int m0 = bm << 7, n0 = bn << 7;
  const int tid = threadIdx.x;
  const int wave = tid >> 6, lane = tid & 63;
  const int wr = (wave >> 1) << 6, wc = (wave & 1) << 6;
  const int lrow = lane & 15, lquad = lane >> 4;

  floatx4 acc[4][4];
  #pragma unroll
  for (int i = 0; i < 4; ++i)
    #pragma unroll
    for (int j = 0; j < 4; ++j) { floatx4 z = {0.f,0.f,0.f,0.f}; acc[i][j] = z; }

  const u16* a0p = A  + (size_t)m0 * K;
  const u16* b0p = Bt + (size_t)n0 * K;
  const int c0 = tid, c1 = 256 + tid;
  const int ar0 = c0 >> 2, as0 = (c0 & 3) * 8;
  const int ar1 = c1 >> 2, as1 = (c1 & 3) * 8;

  for (int k0 = 0; k0 < K; k0 += 32) {
    __builtin_amdgcn_global_load_lds((gas_t)(a0p + (size_t)ar0*K + k0 + as0), (las_t)(&As[c0*8]), 16, 0, 0);
    __builtin_amdgcn_global_load_lds((gas_t)(a0p + (size_t)ar1*K + k0 + as1), (las_t)(&As[c1*8]), 16, 0, 0);
    __builtin_amdgcn_global_load_lds((gas_t)(b0p + (size_t)ar0*K + k0 + as0), (las_t)(&Bs[c0*8]), 16, 0, 0);
    __builtin_amdgcn_global_load_lds((gas_t)(b0p + (size_t)ar1*K + k0 + as1), (las_t)(&Bs[c1*8]), 16, 0, 0);
    __syncthreads();
    short8 af[4], bf[4];
    #pragma unroll
    for (int i = 0; i < 4; ++i) af[i] = *(const short8*)&As[(wr + i*16 + lrow)*32 + lquad*8];
    #pragma unroll
    for (int j = 0; j < 4; ++j) bf[j] = *(const short8*)&Bs[(wc + j*16 + lrow)*32 + lquad*8];
    #pragma unroll
    for (int i = 0; i < 4; ++i)
      #pragma unroll
      for (int j = 0; j < 4; ++j)
        acc[i][j] = __builtin_amdgcn_mfma_f32_16x16x32_bf16(af[i], bf[j], acc[i][j], 0, 0, 0);
    __syncthreads();
  }

  const bool hasb = (flags & 1) != 0;
  const bool dorelu = (flags & 2) != 0;
  #pragma unroll
  for (int j = 0; j < 4; ++j) {
    const int col = n0 + wc + j*16 + lrow;
    const float bv = hasb ? bias[col] : 0.f;
    #pragma unroll
    for (int i = 0; i < 4; ++i) {
      const int r0 = m0 + wr + i*16 + lquad*4;
      #pragma unroll
      for (int v = 0; v < 4; ++v) {
        float val = acc[i][j][v] + bv;
        if (dorelu) val = fmaxf(val, 0.f);
        const size_t off = (size_t)(r0 + v) * N + col;
        if (outF) outF[off] = val;
        else      outB[off] = f2b(val);
      }
    }
  }
}

// ---------------------------------------------------------------------------
// Flash attention with relative-position bias, one block per (b, h, q-tile 64)
// qkv: [8192][1536] bf16, rel: [257][64] f32, ctx: [8192][512] bf16
// ---------------------------------------------------------------------------
__global__ __launch_bounds__(256) void attn_kernel(
    const u16* __restrict__ qkv, const float* __restrict__ rel, u16* __restrict__ ctx)
{
  const int qt = blockIdx.x;  // 0..7
  const int h  = blockIdx.y;  // 0..7
  const int b  = blockIdx.z;  // 0..15
  const int t  = threadIdx.x;

  __shared__ u16 Qs[64][66];
  __shared__ u16 KV[64][66];
  __shared__ u16 Ps[64][66];
  __shared__ u16 Pr[64][257];   // proj[q][j] = q_vec . rel[j]  (bf16)

  const int lrow = t >> 2;
  const int lcg  = (t & 3) * 16;

  { // load Q tile
    const u16* src = qkv + (size_t)(b*SEQ + qt*64 + lrow) * 1536 + h*64 + lcg;
    uint4 p0 = *(const uint4*)(src);
    uint4 p1 = *(const uint4*)(src + 8);
    u32* d0 = (u32*)&Qs[lrow][lcg];
    d0[0]=p0.x; d0[1]=p0.y; d0[2]=p0.z; d0[3]=p0.w;
    d0[4]=p1.x; d0[5]=p1.y; d0[6]=p1.z; d0[7]=p1.w;
  }
  __syncthreads();

  { // proj table: Pr[q][j] = Qs[q][:] . rel[j][:]
    const int q = t >> 2, jg = t & 3;
    for (int p = 0; p < 65; ++p) {
      const int j = p*4 + jg;
      if (j < 257) {
        const float* e = rel + j*64;
        float s = 0.f;
        #pragma unroll
        for (int dd = 0; dd < 64; dd += 8) {
          float4 e0 = *(const float4*)(e + dd);
          float4 e1 = *(const float4*)(e + dd + 4);
          const u32* qq = (const u32*)&Qs[q][dd];
          u32 q0v = qq[0], q1v = qq[1], q2v = qq[2], q3v = qq[3];
          s += lo16(q0v)*e0.x + hi16(q0v)*e0.y
             + lo16(q1v)*e0.z + hi16(q1v)*e0.w
             + lo16(q2v)*e1.x + hi16(q2v)*e1.y
             + lo16(q3v)*e1.z + hi16(q3v)*e1.w;
        }
        Pr[q][j] = f2b(s);
      }
    }
  }

  const int qg = t >> 4, kg = t & 15;
  const int q0 = qg * 4;

  float m_i[4], l_i[4], o[4][4];
  #pragma unroll
  for (int i = 0; i < 4; ++i) {
    m_i[i] = -1e30f; l_i[i] = 0.f;
    #pragma unroll
    for (int j = 0; j < 4; ++j) o[i][j] = 0.f;
  }

  for (int kt = 0; kt < 8; ++kt) {
    __syncthreads();
    { // K tile -> KV
      const u16* kp = qkv + (size_t)(b*SEQ + kt*64 + lrow) * 1536 + 512 + h*64 + lcg;
      uint4 p0 = *(const uint4*)(kp);
      uint4 p1 = *(const uint4*)(kp + 8);
      u32* d0 = (u32*)&KV[lrow][lcg];
      d0[0]=p0.x; d0[1]=p0.y; d0[2]=p0.z; d0[3]=p0.w;
      d0[4]=p1.x; d0[5]=p1.y; d0[6]=p1.z; d0[7]=p1.w;
    }
    __syncthreads();

    float sc[4][4];
    #pragma unroll
    for (int i = 0; i < 4; ++i)
      #pragma unroll
      for (int j = 0; j < 4; ++j) sc[i][j] = 0.f;

    for (int d = 0; d < 64; d += 2) {
      u32 qv[4], kv[4];
      #pragma unroll
      for (int i = 0; i < 4; ++i) qv[i] = *(const u32*)&Qs[q0+i][d];
      #pragma unroll
      for (int j = 0; j < 4; ++j) kv[j] = *(const u32*)&KV[kg*4+j][d];
      float kx[4], ky[4];
      #pragma unroll
      for (int j = 0; j < 4; ++j) { kx[j] = lo16(kv[j]); ky[j] = hi16(kv[j]); }
      #pragma unroll
      for (int i = 0; i < 4; ++i) {
        const float qx = lo16(qv[i]), qy = hi16(qv[i]);
        #pragma unroll
        for (int j = 0; j < 4; ++j) sc[i][j] += qx*kx[j] + qy*ky[j];
      }
    }

    const int qpos0 = qt*64 + q0;
    const int kpos0 = kt*64 + kg*4;
    #pragma unroll
    for (int i = 0; i < 4; ++i) {
      #pragma unroll
      for (int j = 0; j < 4; ++j) {
        int dd = (kpos0 + j) - (qpos0 + i);
        dd = dd < -128 ? -128 : (dd > 128 ? 128 : dd);
        sc[i][j] = sc[i][j]*0.125f + b2f(Pr[q0+i][dd + 128]);
      }
    }
    #pragma unroll
    for (int i = 0; i < 4; ++i) {
      float r = fmaxf(fmaxf(sc[i][0], sc[i][1]), fmaxf(sc[i][2], sc[i][3]));
      r = fmaxf(r, __shfl_xor(r, 1));
      r = fmaxf(r, __shfl_xor(r, 2));
      r = fmaxf(r, __shfl_xor(r, 4));
      r = fmaxf(r, __shfl_xor(r, 8));
      const float mn = fmaxf(m_i[i], r);
      const float al = __expf(m_i[i] - mn);
      m_i[i] = mn;
      float ps = 0.f;
      #pragma unroll
      for (int j = 0; j < 4; ++j) { sc[i][j] = __expf(sc[i][j] - mn); ps += sc[i][j]; }
      ps += __shfl_xor(ps, 1);
      ps += __shfl_xor(ps, 2);
      ps += __shfl_xor(ps, 4);
      ps += __shfl_xor(ps, 8);
      l_i[i] = l_i[i]*al + ps;
      #pragma unroll
      for (int j = 0; j < 4; ++j) o[i][j] *= al;
      *(u32*)&Ps[q0+i][kg*4]   = pack2(sc[i][0], sc[i][1]);
      *(u32*)&Ps[q0+i][kg*4+2] = pack2(sc[i][2], sc[i][3]);
    }
    __syncthreads();
    { // V tile -> KV (overwrite K)
      const u16* vp = qkv + (size_t)(b*SEQ + kt*64 + lrow) * 1536 + 1024 + h*64 + lcg;
      uint4 p0 = *(const uint4*)(vp);
      uint4 p1 = *(const uint4*)(vp + 8);
      u32* d0 = (u32*)&KV[lrow][lcg];
      d0[0]=p0.x; d0[1]=p0.y; d0[2]=p0.z; d0[3]=p0.w;
      d0[4]=p1.x; d0[5]=p1.y; d0[6]=p1.z; d0[7]=p1.w;
    }
    __syncthreads();
    for (int k = 0; k < 64; k += 2) {
      float pA[4], pB[4];
      #pragma unroll
      for (int i = 0; i < 4; ++i) {
        const u32 pp = *(const u32*)&Ps[q0+i][k];
        pA[i] = lo16(pp); pB[i] = hi16(pp);
      }
      const u32 a0 = *(const u32*)&KV[k][kg*4];
      const u32 a1 = *(const u32*)&KV[k][kg*4+2];
      const u32 b0 = *(const u32*)&KV[k+1][kg*4];
      const u32 b1 = *(const u32*)&KV[k+1][kg*4+2];
      const float vA[4] = {lo16(a0), hi16(a0), lo16(a1), hi16(a1)};
      const float vB[4] = {lo16(b0), hi16(b0), lo16(b1), hi16(b1)};
      #pragma unroll
      for (int i = 0; i < 4; ++i)
        #pragma unroll
        for (int j = 0; j < 4; ++j)
          o[i][j] += pA[i]*vA[j] + pB[i]*vB[j];
    }
  }

  #pragma unroll
  for (int i = 0; i < 4; ++i) {
    const float inv = 1.f / l_i[i];
    u32* dp = (u32*)(ctx + (size_t)(b*SEQ + qt*64 + q0 + i) * 512 + h*64 + kg*4);
    dp[0] = pack2(o[i][0]*inv, o[i][1]*inv);
    dp[1] = pack2(o[i][2]*inv, o[i][3]*inv);
  }
}

// ---------------------------------------------------------------------------
// LayerNorm over D=512: h = LN(res (+ add)) * g + b  -> hf (f32) + hb (bf16)
// g, b are f32.
// ---------------------------------------------------------------------------
__global__ __launch_bounds__(128) void ln_kernel(
    const float* __restrict__ res, const float* __restrict__ add,
    const float* __restrict__ g, const float* __restrict__ be,
    float* __restrict__ hf, u16* __restrict__ hb)
{
  const int row = blockIdx.x, t = threadIdx.x;
  const size_t base = (size_t)row * 512;
  float4 x = *(const float4*)(res + base + t*4);
  if (add) {
    const float4 a = *(const float4*)(add + base + t*4);
    x.x += a.x; x.y += a.y; x.z += a.z; x.w += a.w;
  }
  float s = x.x + x.y + x.z + x.w;
  #pragma unroll
  for (int off = 32; off > 0; off >>= 1) s += __shfl_down(s, off);
  __shared__ float red[2];
  const int wv = t >> 6, ln = t & 63;
  if (ln == 0) red[wv] = s;
  __syncthreads();
  const float mean = (red[0] + red[1]) * (1.f/512.f);
  const float dx0 = x.x-mean, dx1 = x.y-mean, dx2 = x.z-mean, dx3 = x.w-mean;
  float vs = dx0*dx0 + dx1*dx1 + dx2*dx2 + dx3*dx3;
  __syncthreads();
  #pragma unroll
  for (int off = 32; off > 0; off >>= 1) vs += __shfl_down(vs, off);
  if (ln == 0) red[wv] = vs;
  __syncthreads();
  const float var = (red[0] + red[1]) * (1.f/512.f);
  const float inv = 1.f / sqrtf(var + 1e-5f);
  const float4 gv = *(const float4*)(g + t*4);
  const float4 bv = *(const float4*)(be + t*4);
  const float y0 = dx0*inv*gv.x + bv.x;
  const float y1 = dx1*inv*gv.y + bv.y;
  const float y2 = dx2*inv*gv.z + bv.z;
  const float y3 = dx3*inv*gv.w + bv.w;
  *(float4*)(hf + base + t*4) = make_float4(y0, y1, y2, y3);
  u32* hp = (u32*)(hb + base + t*4);
  hp[0] = pack2(y0, y1); hp[1] = pack2(y2, y3);
}

// ---------------------------------------------------------------------------
// out[row] = hd1[row][:] . p2_w + p2_b   (256-dot, one wave per row)
// d_out is FLOAT32 (reference output dtype).
// ---------------------------------------------------------------------------
__global__ __launch_bounds__(256) void head2_kernel(
    const u16* __restrict__ hd1, const float* __restrict__ p2w,
    const float* __restrict__ p2b, float* __restrict__ out)
{
  const int wv = threadIdx.x >> 6, ln = threadIdx.x & 63;
  const int row = blockIdx.x * 4 + wv;
  const u16* hp = hd1 + (size_t)row * 256 + ln*4;
  const u32 h0 = *(const u32*)hp, h1 = *(const u32*)(hp + 2);
  const float4 w = *(const float4*)(p2w + ln*4);
  float acc = lo16(h0)*w.x + hi16(h0)*w.y + lo16(h1)*w.z + hi16(h1)*w.w;
  #pragma unroll
  for (int off = 1; off < 64; off <<= 1) acc += __shfl_xor(acc, off);
  if (ln == 0) out[row] = acc + p2b[0];
}

// ---------------------------------------------------------------------------
extern "C" void kernel_launch(void* const* d_in, const int* in_sizes, int n_in,
                              void* d_out, int out_size, void* d_ws, size_t ws_size,
                              hipStream_t stream) {
  (void)in_sizes; (void)n_in; (void)out_size; (void)ws_size;
  const float* X    = (const float*)d_in[0];
  const float* INW  = (const float*)d_in[1];
  const float* INB  = (const float*)d_in[2];
  const float* WQ   = (const float*)d_in[3];
  const float* WK   = (const float*)d_in[4];
  const float* WV   = (const float*)d_in[5];
  const float* WO   = (const float*)d_in[6];
  const float* BO   = (const float*)d_in[7];
  const float* REL  = (const float*)d_in[8];
  const float* W1   = (const float*)d_in[9];
  const float* B1   = (const float*)d_in[10];
  const float* W2   = (const float*)d_in[11];
  const float* B2   = (const float*)d_in[12];
  const float* LN1G = (const float*)d_in[13];
  const float* LN1B = (const float*)d_in[14];
  const float* LN2G = (const float*)d_in[15];
  const float* LN2B = (const float*)d_in[16];
  const float* ONG  = (const float*)d_in[17];
  const float* ONB  = (const float*)d_in[18];
  const float* P1W  = (const float*)d_in[19];
  const float* P1B  = (const float*)d_in[20];
  const float* P2W  = (const float*)d_in[21];
  const float* P2B  = (const float*)d_in[22];
  float* out = (float*)d_out;

  char* ws = (char*)d_ws;
  u16*   wT   = (u16*)(ws + OFF_WT);
  float* hF   = (float*)(ws + OFF_HF);
  u16*   hB   = (u16*)(ws + OFF_HB);
  u16*   qkv  = (u16*)(ws + OFF_QKV);
  u16*   ctx  = (u16*)(ws + OFF_CTX);
  float* gout = (float*)(ws + OFF_GOUT);
  u16*   ff   = (u16*)(ws + OFF_FF);
  u16*   hd1  = (u16*)(ws + OFF_HD1);

  transpose_all<<<4640, 256, 0, stream>>>(WQ, WK, WV, WO, W1, W2, P1W, wT);
  input_proj<<<NTOK, 128, 0, stream>>>(X, INW, INB, hF, hB);

  for (int l = 0; l < NLAYER; ++l) {
    const u16* wTl = wT + (size_t)l * LSTRIDE;
    // QKV fused: [8192,512] @ [512,1536]
    gemm_bt<<<768, 256, 0, stream>>>(hB, wTl, nullptr, nullptr, qkv, 8192, 1536, 512, 0);
    attn_kernel<<<dim3(8, 8, 16), 256, 0, stream>>>(qkv, REL + l*16448, ctx);
    // Wo + bo -> f32
    gemm_bt<<<256, 256, 0, stream>>>(ctx, wTl + 786432, BO + l*512, gout, nullptr, 8192, 512, 512, 1);
    ln_kernel<<<NTOK, 128, 0, stream>>>(hF, gout, LN1G + l*512, LN1B + l*512, hF, hB);
    // FFN1: relu(h @ w1 + b1) -> bf16
    gemm_bt<<<1024, 256, 0, stream>>>(hB, wTl + 1048576, B1 + l*2048, nullptr, ff, 8192, 2048, 512, 3);
    // FFN2: ff @ w2 + b2 -> f32
    gemm_bt<<<256, 256, 0, stream>>>(ff, wTl + 2097152, B2 + l*512, gout, nullptr, 8192, 512, 2048, 1);
    ln_kernel<<<NTOK, 128, 0, stream>>>(hF, gout, LN2G + l*512, LN2B + l*512, hF, hB);
  }
  ln_kernel<<<NTOK, 128, 0, stream>>>(hF, nullptr, ONG, ONB, hF, hB);
  // head: relu(h @ p1_w + p1_b) -> bf16 [8192][256]
  gemm_bt<<<128, 256, 0, stream>>>(hB, wT + P1T_OFF, P1B, nullptr, hd1, 8192, 256, 512, 3);
  head2_kernel<<<2048, 256, 0, stream>>>(hd1, P2W, P2B, out);
}

// Round 4
// 1544.177 us; speedup vs baseline: 3.0944x; 3.0944x over previous
//
#include <hip/hip_runtime.h>

typedef unsigned short u16;
typedef unsigned int   u32;
typedef short   short8  __attribute__((ext_vector_type(8)));
typedef float   floatx4 __attribute__((ext_vector_type(4)));

#define NTOK 8192
#define SEQ  512
#define NLAYER 6

// ---- workspace layout (bytes) ----
#define OFF_WT   ((size_t)0)          // transposed weights (bf16), 19,005,440 u16
#define OFF_HF   ((size_t)38010880)   // h fp32   [8192][512]
#define OFF_HB   ((size_t)54788096)   // h bf16   [8192][512]
#define OFF_QKV  ((size_t)63176704)   // qkv bf16 [8192][1536]
#define OFF_CTX  ((size_t)88342528)   // ctx bf16 [8192][512]
#define OFF_GOUT ((size_t)96731136)   // gemm out fp32 [8192][512]
#define OFF_FF   ((size_t)113508352)  // ff bf16  [8192][2048]  (33.5 MB)
#define OFF_HD1  ((size_t)147062784)  // head1 bf16 [8192][256]
// attention scratch overlapped into the ff region (dead during attn phase):
#define OFF_VT   OFF_FF                       // vT bf16 [128 bh][64 d][512 s] = 8,388,608 B
#define OFF_RELB (OFF_FF + (size_t)8388608)   // relB bf16 [272][64] = 34,816 B

#define LSTRIDE 3145728   // wT elems per layer: [QT;KT;VT](1536x512), WoT, w1T(2048x512), w2T(512x2048)
#define P1T_OFF 18874368  // p1T [256][512]

__device__ __forceinline__ float b2f(u16 v) { return __uint_as_float(((u32)v) << 16); }
__device__ __forceinline__ float lo16(u32 v) { return __uint_as_float(v << 16); }
__device__ __forceinline__ float hi16(u32 v) { return __uint_as_float(v & 0xffff0000u); }
__device__ __forceinline__ u16 f2b(float f) {
  u32 x = __float_as_uint(f);
  return (u16)((x + 0x7fffu + ((x >> 16) & 1u)) >> 16);
}
__device__ __forceinline__ u32 pack2(float a, float b) {
  return (u32)f2b(a) | ((u32)f2b(b) << 16);
}

typedef __attribute__((address_space(1))) void* gas_t;
typedef __attribute__((address_space(3))) void* las_t;

// ---------------------------------------------------------------------------
// Transpose all f32 weight matrices into wT (bf16 [N][K] for gemm_bt).
// ---------------------------------------------------------------------------
__global__ __launch_bounds__(256) void transpose_all(
    const float* __restrict__ Wq, const float* __restrict__ Wk,
    const float* __restrict__ Wv, const float* __restrict__ Wo,
    const float* __restrict__ w1, const float* __restrict__ w2,
    const float* __restrict__ p1, u16* __restrict__ wT)
{
  __shared__ u16 tile[64][65];
  const int tb = blockIdx.x;
  const float* src; u16* dst; int R, C, tidx;
  if (tb < 4608) {
    const int l = tb / 768, r = tb % 768;
    const size_t lofs = (size_t)l * LSTRIDE;
    if (r < 256) {
      const int m = r >> 6; tidx = r & 63; R = 512; C = 512;
      const float* bases[4] = {Wq, Wk, Wv, Wo};
      src = bases[m] + (size_t)l * 262144;
      dst = wT + lofs + (size_t)m * 262144;
    } else if (r < 512) {
      tidx = r - 256; R = 512; C = 2048;
      src = w1 + (size_t)l * 1048576; dst = wT + lofs + 1048576;
    } else {
      tidx = r - 512; R = 2048; C = 512;
      src = w2 + (size_t)l * 1048576; dst = wT + lofs + 2097152;
    }
  } else {
    tidx = tb - 4608; R = 512; C = 256;
    src = p1; dst = wT + P1T_OFF;
  }
  const int tcn = C >> 6;
  const int tr = tidx / tcn, tc = tidx % tcn;
  const int th = threadIdx.x;
  {
    const int lr = th >> 2, cg = (th & 3) * 16;
    const float* sp = src + (size_t)(tr*64 + lr) * C + tc*64 + cg;
    float4 f0 = *(const float4*)(sp);
    float4 f1 = *(const float4*)(sp + 4);
    float4 f2 = *(const float4*)(sp + 8);
    float4 f3 = *(const float4*)(sp + 12);
    u16* tp = &tile[lr][cg];
    tp[0]=f2b(f0.x); tp[1]=f2b(f0.y); tp[2]=f2b(f0.z); tp[3]=f2b(f0.w);
    tp[4]=f2b(f1.x); tp[5]=f2b(f1.y); tp[6]=f2b(f1.z); tp[7]=f2b(f1.w);
    tp[8]=f2b(f2.x); tp[9]=f2b(f2.y); tp[10]=f2b(f2.z); tp[11]=f2b(f2.w);
    tp[12]=f2b(f3.x); tp[13]=f2b(f3.y); tp[14]=f2b(f3.z); tp[15]=f2b(f3.w);
  }
  __syncthreads();
  {
    const int oc = th >> 2, rg = (th & 3) * 16;
    u32 wds[8];
    #pragma unroll
    for (int i = 0; i < 8; ++i)
      wds[i] = (u32)tile[rg + 2*i][oc] | ((u32)tile[rg + 2*i + 1][oc] << 16);
    u16* dp = dst + (size_t)(tc*64 + oc) * R + tr*64 + rg;
    uint4 o0; o0.x=wds[0]; o0.y=wds[1]; o0.z=wds[2]; o0.w=wds[3];
    uint4 o1; o1.x=wds[4]; o1.y=wds[5]; o1.z=wds[6]; o1.w=wds[7];
    *(uint4*)dp = o0;
    *(uint4*)(dp + 8) = o1;
  }
}

// ---------------------------------------------------------------------------
// h = x @ in_w + in_b + sinusoidal_pe   (K=50, exact f32)
// ---------------------------------------------------------------------------
__global__ __launch_bounds__(128) void input_proj(
    const float* __restrict__ x, const float* __restrict__ w, const float* __restrict__ ib,
    float* __restrict__ hf, u16* __restrict__ hb)
{
  const int row = blockIdx.x, t = threadIdx.x;
  const int s = row & (SEQ - 1);
  __shared__ float xs[50];
  if (t < 50) xs[t] = x[row*50 + t];
  __syncthreads();
  #pragma unroll
  for (int rep = 0; rep < 4; ++rep) {
    const int d = rep*128 + t;
    float acc = ib[d];
    #pragma unroll
    for (int i = 0; i < 50; ++i) acc += xs[i] * w[i*512 + d];
    const int ii = d >> 1;
    const float dv = __expf((float)(2*ii) * -0.017988946f); // -ln(10000)/512
    const float ang = (float)s * dv;
    const float pe = (d & 1) ? cosf(ang) : sinf(ang);
    const float v = acc + pe;
    hf[(size_t)row*512 + d] = v;
    hb[(size_t)row*512 + d] = f2b(v);
  }
}

// ---------------------------------------------------------------------------
// C[M][N] = A[M][K](bf16) @ Bt[N][K]^T (+bias f32)(relu?) -> f32 or bf16
// ---------------------------------------------------------------------------
__global__ __launch_bounds__(256) void gemm_bt(
    const u16* __restrict__ A, const u16* __restrict__ Bt,
    const float* __restrict__ bias, float* __restrict__ outF, u16* __restrict__ outB,
    const int M, const int N, const int K, const int flags)
{
  __shared__ __align__(16) u16 As[128*32];
  __shared__ __align__(16) u16 Bs[128*32];
  const int nb = N >> 7;
  const int bm = blockIdx.x / nb, bn = blockIdx.x % nb;
  const int m0 = bm << 7, n0 = bn << 7;
  const int tid = threadIdx.x;
  const int wave = tid >> 6, lane = tid & 63;
  const int wr = (wave >> 1) << 6, wc = (wave & 1) << 6;
  const int lrow = lane & 15, lquad = lane >> 4;

  floatx4 acc[4][4];
  #pragma unroll
  for (int i = 0; i < 4; ++i)
    #pragma unroll
    for (int j = 0; j < 4; ++j) { floatx4 z = {0.f,0.f,0.f,0.f}; acc[i][j] = z; }

  const u16* a0p = A  + (size_t)m0 * K;
  const u16* b0p = Bt + (size_t)n0 * K;
  const int c0 = tid, c1 = 256 + tid;
  const int ar0 = c0 >> 2, as0 = (c0 & 3) * 8;
  const int ar1 = c1 >> 2, as1 = (c1 & 3) * 8;

  for (int k0 = 0; k0 < K; k0 += 32) {
    __builtin_amdgcn_global_load_lds((gas_t)(a0p + (size_t)ar0*K + k0 + as0), (las_t)(&As[c0*8]), 16, 0, 0);
    __builtin_amdgcn_global_load_lds((gas_t)(a0p + (size_t)ar1*K + k0 + as1), (las_t)(&As[c1*8]), 16, 0, 0);
    __builtin_amdgcn_global_load_lds((gas_t)(b0p + (size_t)ar0*K + k0 + as0), (las_t)(&Bs[c0*8]), 16, 0, 0);
    __builtin_amdgcn_global_load_lds((gas_t)(b0p + (size_t)ar1*K + k0 + as1), (las_t)(&Bs[c1*8]), 16, 0, 0);
    __syncthreads();
    short8 af[4], bf[4];
    #pragma unroll
    for (int i = 0; i < 4; ++i) af[i] = *(const short8*)&As[(wr + i*16 + lrow)*32 + lquad*8];
    #pragma unroll
    for (int j = 0; j < 4; ++j) bf[j] = *(const short8*)&Bs[(wc + j*16 + lrow)*32 + lquad*8];
    #pragma unroll
    for (int i = 0; i < 4; ++i)
      #pragma unroll
      for (int j = 0; j < 4; ++j)
        acc[i][j] = __builtin_amdgcn_mfma_f32_16x16x32_bf16(af[i], bf[j], acc[i][j], 0, 0, 0);
    __syncthreads();
  }

  const bool hasb = (flags & 1) != 0;
  const bool dorelu = (flags & 2) != 0;
  #pragma unroll
  for (int j = 0; j < 4; ++j) {
    const int col = n0 + wc + j*16 + lrow;
    const float bv = hasb ? bias[col] : 0.f;
    #pragma unroll
    for (int i = 0; i < 4; ++i) {
      const int r0 = m0 + wr + i*16 + lquad*4;
      #pragma unroll
      for (int v = 0; v < 4; ++v) {
        float val = acc[i][j][v] + bv;
        if (dorelu) val = fmaxf(val, 0.f);
        const size_t off = (size_t)(r0 + v) * N + col;
        if (outF) outF[off] = val;
        else      outB[off] = f2b(val);
      }
    }
  }
}

// ---------------------------------------------------------------------------
// V transpose: qkv v-part [b*512+s][1024 + h*64 + d] -> vT[(b*8+h)*64+d][512 s]
// ---------------------------------------------------------------------------
__global__ __launch_bounds__(256) void v_transpose(
    const u16* __restrict__ qkv, u16* __restrict__ vT)
{
  const int kt = blockIdx.x, h = blockIdx.y, b = blockIdx.z;
  __shared__ u16 tile[64*72];
  const int t = threadIdx.x;
  const int row = t >> 2, cg = (t & 3) * 16;
  const u16* sp = qkv + (size_t)(b*512 + kt*64 + row)*1536 + 1024 + h*64 + cg;
  uint4 a0 = *(const uint4*)sp;
  uint4 a1 = *(const uint4*)(sp + 8);
  *(uint4*)&tile[row*72 + cg]     = a0;
  *(uint4*)&tile[row*72 + cg + 8] = a1;
  __syncthreads();
  const int d = row;
  u32 wds[8];
  #pragma unroll
  for (int i = 0; i < 8; ++i)
    wds[i] = (u32)tile[(cg + 2*i)*72 + d] | ((u32)tile[(cg + 2*i + 1)*72 + d] << 16);
  u16* dp = vT + ((size_t)(b*8 + h)*64 + d)*512 + kt*64 + cg;
  uint4 o0; o0.x=wds[0]; o0.y=wds[1]; o0.z=wds[2]; o0.w=wds[3];
  uint4 o1; o1.x=wds[4]; o1.y=wds[5]; o1.z=wds[6]; o1.w=wds[7];
  *(uint4*)dp = o0;
  *(uint4*)(dp + 8) = o1;
}

// ---------------------------------------------------------------------------
// rel_emb layer slice f32 [257][64] -> bf16 relB [272 rows alloc][64]
// ---------------------------------------------------------------------------
__global__ __launch_bounds__(256) void cvt_rel(
    const float* __restrict__ rel, u16* __restrict__ relB)
{
  const int i = blockIdx.x*256 + threadIdx.x;
  if (i < 257*64) relB[i] = f2b(rel[i]);
}

// ---------------------------------------------------------------------------
// MFMA flash attention with relative-position bias.
// Block = (qt, h, b), 256 thr = 4 waves; wave w owns q rows [w*16, w*16+16).
// qkv bf16 [8192][1536]; vT bf16 [(b*8+h)*64+d][512]; relB bf16 [272][64];
// ctx bf16 [8192][512].
// ---------------------------------------------------------------------------
__global__ __launch_bounds__(256) void attn_mfma(
    const u16* __restrict__ qkv, const u16* __restrict__ vT,
    const u16* __restrict__ relB, u16* __restrict__ ctx)
{
  const int qt = blockIdx.x, h = blockIdx.y, b = blockIdx.z;
  const int t = threadIdx.x, w = t >> 6, lane = t & 63;
  const int lr = lane & 15, quad = lane >> 4;

  __shared__ __align__(16) u16 Ks[64*72];
  __shared__ __align__(16) u16 Vs[64*72];
  __shared__ __align__(16) u16 Ps[64*72];
  __shared__ __align__(16) u16 Pr[64*280];   // proj table, rows wave-private

  const size_t token0 = (size_t)b*512 + qt*64;

  // Q A-fragments (held in regs for whole kernel): rows w*16+lr, k = quad*8(+32)
  short8 af0, af1;
  {
    const u16* qp = qkv + (token0 + w*16 + lr)*1536 + h*64 + quad*8;
    af0 = *(const short8*)(qp);
    af1 = *(const short8*)(qp + 32);
  }

  // Pr[q][j] = Q[q] . relB[j]  via MFMA (each wave: its 16 rows x 272 cols)
  #pragma unroll 4
  for (int nt = 0; nt < 17; ++nt) {
    const u16* rp = relB + (nt*16 + lr)*64 + quad*8;
    short8 rb0 = *(const short8*)(rp);
    short8 rb1 = *(const short8*)(rp + 32);
    floatx4 c = {0.f,0.f,0.f,0.f};
    c = __builtin_amdgcn_mfma_f32_16x16x32_bf16(af0, rb0, c, 0, 0, 0);
    c = __builtin_amdgcn_mfma_f32_16x16x32_bf16(af1, rb1, c, 0, 0, 0);
    #pragma unroll
    for (int r = 0; r < 4; ++r)
      Pr[(w*16 + quad*4 + r)*280 + nt*16 + lr] = f2b(c[r]);
  }

  float m_i[4], l_i[4];
  floatx4 oacc[4];
  #pragma unroll
  for (int r = 0; r < 4; ++r) { m_i[r] = -1e30f; l_i[r] = 0.f; }
  #pragma unroll
  for (int n = 0; n < 4; ++n) { floatx4 z = {0.f,0.f,0.f,0.f}; oacc[n] = z; }

  const int srow = t >> 2, scol = (t & 3) * 16;
  const u16* kbase = qkv + (size_t)b*512*1536 + 512 + h*64;
  const u16* vbase = vT + (size_t)(b*8 + h)*64*512;
  const int qglob = qt*64 + w*16 + quad*4;

  for (int kt = 0; kt < 8; ++kt) {
    __syncthreads();
    { // stage K tile [k][d] and Vt tile [d][k] into padded LDS
      const u16* kp = kbase + (size_t)(kt*64 + srow)*1536 + scol;
      uint4 k0 = *(const uint4*)kp;
      uint4 k1 = *(const uint4*)(kp + 8);
      const u16* vp = vbase + (size_t)srow*512 + kt*64 + scol;
      uint4 v0 = *(const uint4*)vp;
      uint4 v1 = *(const uint4*)(vp + 8);
      *(uint4*)&Ks[srow*72 + scol]     = k0;
      *(uint4*)&Ks[srow*72 + scol + 8] = k1;
      *(uint4*)&Vs[srow*72 + scol]     = v0;
      *(uint4*)&Vs[srow*72 + scol + 8] = v1;
    }
    __syncthreads();

    // S = Q . K^T  (wave's 16 q rows x 64 k cols)
    floatx4 s4[4];
    #pragma unroll
    for (int nt = 0; nt < 4; ++nt) {
      short8 kb0 = *(const short8*)&Ks[(nt*16 + lr)*72 + quad*8];
      short8 kb1 = *(const short8*)&Ks[(nt*16 + lr)*72 + 32 + quad*8];
      floatx4 c = {0.f,0.f,0.f,0.f};
      c = __builtin_amdgcn_mfma_f32_16x16x32_bf16(af0, kb0, c, 0, 0, 0);
      c = __builtin_amdgcn_mfma_f32_16x16x32_bf16(af1, kb1, c, 0, 0, 0);
      s4[nt] = c;
    }

    // bias gather + scale, online softmax per row r (rows quad*4+r)
    const int kpos = kt*64 + lr;
    #pragma unroll
    for (int r = 0; r < 4; ++r) {
      const int qg = qglob + r;
      const int prrow = (w*16 + quad*4 + r)*280;
      float sc[4];
      #pragma unroll
      for (int nt = 0; nt < 4; ++nt) {
        int dd = (kpos + nt*16) - qg;
        dd = dd < -128 ? -128 : (dd > 128 ? 128 : dd);
        sc[nt] = fmaf(s4[nt][r], 0.125f, b2f(Pr[prrow + dd + 128]));
      }
      float mx = fmaxf(fmaxf(sc[0], sc[1]), fmaxf(sc[2], sc[3]));
      mx = fmaxf(mx, __shfl_xor(mx, 1));
      mx = fmaxf(mx, __shfl_xor(mx, 2));
      mx = fmaxf(mx, __shfl_xor(mx, 4));
      mx = fmaxf(mx, __shfl_xor(mx, 8));
      const float mn = fmaxf(m_i[r], mx);
      const float al = __expf(m_i[r] - mn);
      m_i[r] = mn;
      float p0 = __expf(sc[0] - mn), p1 = __expf(sc[1] - mn);
      float p2 = __expf(sc[2] - mn), p3 = __expf(sc[3] - mn);
      float ps = p0 + p1 + p2 + p3;
      ps += __shfl_xor(ps, 1);
      ps += __shfl_xor(ps, 2);
      ps += __shfl_xor(ps, 4);
      ps += __shfl_xor(ps, 8);
      l_i[r] = l_i[r]*al + ps;
      #pragma unroll
      for (int n = 0; n < 4; ++n) oacc[n][r] *= al;
      const int psrow = (w*16 + quad*4 + r)*72;
      Ps[psrow + lr]      = f2b(p0);
      Ps[psrow + 16 + lr] = f2b(p1);
      Ps[psrow + 32 + lr] = f2b(p2);
      Ps[psrow + 48 + lr] = f2b(p3);
    }

    // O += P . V   (A-frag from Ps, wave-private rows; B-frag from Vs [d][k])
    short8 pf0 = *(const short8*)&Ps[(w*16 + lr)*72 + quad*8];
    short8 pf1 = *(const short8*)&Ps[(w*16 + lr)*72 + 32 + quad*8];
    #pragma unroll
    for (int nd = 0; nd < 4; ++nd) {
      short8 vb0 = *(const short8*)&Vs[(nd*16 + lr)*72 + quad*8];
      short8 vb1 = *(const short8*)&Vs[(nd*16 + lr)*72 + 32 + quad*8];
      oacc[nd] = __builtin_amdgcn_mfma_f32_16x16x32_bf16(pf0, vb0, oacc[nd], 0, 0, 0);
      oacc[nd] = __builtin_amdgcn_mfma_f32_16x16x32_bf16(pf1, vb1, oacc[nd], 0, 0, 0);
    }
  }

  // epilogue: ctx[token][h*64 + d]
  #pragma unroll
  for (int r = 0; r < 4; ++r) {
    const float inv = 1.f / l_i[r];
    u16* cp = ctx + (token0 + w*16 + quad*4 + r)*512 + h*64 + lr;
    #pragma unroll
    for (int nd = 0; nd < 4; ++nd)
      cp[nd*16] = f2b(oacc[nd][r] * inv);
  }
}

// ---------------------------------------------------------------------------
// LayerNorm over D=512: h = LN(res (+ add)) * g + b  -> hf (f32) + hb (bf16)
// ---------------------------------------------------------------------------
__global__ __launch_bounds__(128) void ln_kernel(
    const float* __restrict__ res, const float* __restrict__ add,
    const float* __restrict__ g, const float* __restrict__ be,
    float* __restrict__ hf, u16* __restrict__ hb)
{
  const int row = blockIdx.x, t = threadIdx.x;
  const size_t base = (size_t)row * 512;
  float4 x = *(const float4*)(res + base + t*4);
  if (add) {
    const float4 a = *(const float4*)(add + base + t*4);
    x.x += a.x; x.y += a.y; x.z += a.z; x.w += a.w;
  }
  float s = x.x + x.y + x.z + x.w;
  #pragma unroll
  for (int off = 32; off > 0; off >>= 1) s += __shfl_down(s, off);
  __shared__ float red[2];
  const int wv = t >> 6, ln = t & 63;
  if (ln == 0) red[wv] = s;
  __syncthreads();
  const float mean = (red[0] + red[1]) * (1.f/512.f);
  const float dx0 = x.x-mean, dx1 = x.y-mean, dx2 = x.z-mean, dx3 = x.w-mean;
  float vs = dx0*dx0 + dx1*dx1 + dx2*dx2 + dx3*dx3;
  __syncthreads();
  #pragma unroll
  for (int off = 32; off > 0; off >>= 1) vs += __shfl_down(vs, off);
  if (ln == 0) red[wv] = vs;
  __syncthreads();
  const float var = (red[0] + red[1]) * (1.f/512.f);
  const float inv = 1.f / sqrtf(var + 1e-5f);
  const float4 gv = *(const float4*)(g + t*4);
  const float4 bv = *(const float4*)(be + t*4);
  const float y0 = dx0*inv*gv.x + bv.x;
  const float y1 = dx1*inv*gv.y + bv.y;
  const float y2 = dx2*inv*gv.z + bv.z;
  const float y3 = dx3*inv*gv.w + bv.w;
  *(float4*)(hf + base + t*4) = make_float4(y0, y1, y2, y3);
  u32* hp = (u32*)(hb + base + t*4);
  hp[0] = pack2(y0, y1); hp[1] = pack2(y2, y3);
}

// ---------------------------------------------------------------------------
// out[row] = hd1[row][:] . p2_w + p2_b   (256-dot, one wave per row), f32 out
// ---------------------------------------------------------------------------
__global__ __launch_bounds__(256) void head2_kernel(
    const u16* __restrict__ hd1, const float* __restrict__ p2w,
    const float* __restrict__ p2b, float* __restrict__ out)
{
  const int wv = threadIdx.x >> 6, ln = threadIdx.x & 63;
  const int row = blockIdx.x * 4 + wv;
  const u16* hp = hd1 + (size_t)row * 256 + ln*4;
  const u32 h0 = *(const u32*)hp, h1 = *(const u32*)(hp + 2);
  const float4 w = *(const float4*)(p2w + ln*4);
  float acc = lo16(h0)*w.x + hi16(h0)*w.y + lo16(h1)*w.z + hi16(h1)*w.w;
  #pragma unroll
  for (int off = 1; off < 64; off <<= 1) acc += __shfl_xor(acc, off);
  if (ln == 0) out[row] = acc + p2b[0];
}

// ---------------------------------------------------------------------------
extern "C" void kernel_launch(void* const* d_in, const int* in_sizes, int n_in,
                              void* d_out, int out_size, void* d_ws, size_t ws_size,
                              hipStream_t stream) {
  (void)in_sizes; (void)n_in; (void)out_size; (void)ws_size;
  const float* X    = (const float*)d_in[0];
  const float* INW  = (const float*)d_in[1];
  const float* INB  = (const float*)d_in[2];
  const float* WQ   = (const float*)d_in[3];
  const float* WK   = (const float*)d_in[4];
  const float* WV   = (const float*)d_in[5];
  const float* WO   = (const float*)d_in[6];
  const float* BO   = (const float*)d_in[7];
  const float* REL  = (const float*)d_in[8];
  const float* W1   = (const float*)d_in[9];
  const float* B1   = (const float*)d_in[10];
  const float* W2   = (const float*)d_in[11];
  const float* B2   = (const float*)d_in[12];
  const float* LN1G = (const float*)d_in[13];
  const float* LN1B = (const float*)d_in[14];
  const float* LN2G = (const float*)d_in[15];
  const float* LN2B = (const float*)d_in[16];
  const float* ONG  = (const float*)d_in[17];
  const float* ONB  = (const float*)d_in[18];
  const float* P1W  = (const float*)d_in[19];
  const float* P1B  = (const float*)d_in[20];
  const float* P2W  = (const float*)d_in[21];
  const float* P2B  = (const float*)d_in[22];
  float* out = (float*)d_out;

  char* ws = (char*)d_ws;
  u16*   wT   = (u16*)(ws + OFF_WT);
  float* hF   = (float*)(ws + OFF_HF);
  u16*   hB   = (u16*)(ws + OFF_HB);
  u16*   qkv  = (u16*)(ws + OFF_QKV);
  u16*   ctx  = (u16*)(ws + OFF_CTX);
  float* gout = (float*)(ws + OFF_GOUT);
  u16*   ff   = (u16*)(ws + OFF_FF);
  u16*   hd1  = (u16*)(ws + OFF_HD1);
  u16*   vTb  = (u16*)(ws + OFF_VT);
  u16*   relB = (u16*)(ws + OFF_RELB);

  transpose_all<<<4640, 256, 0, stream>>>(WQ, WK, WV, WO, W1, W2, P1W, wT);
  input_proj<<<NTOK, 128, 0, stream>>>(X, INW, INB, hF, hB);

  for (int l = 0; l < NLAYER; ++l) {
    const u16* wTl = wT + (size_t)l * LSTRIDE;
    // QKV fused: [8192,512] @ [512,1536]
    gemm_bt<<<768, 256, 0, stream>>>(hB, wTl, nullptr, nullptr, qkv, 8192, 1536, 512, 0);
    v_transpose<<<dim3(8, 8, 16), 256, 0, stream>>>(qkv, vTb);
    cvt_rel<<<65, 256, 0, stream>>>(REL + l*16448, relB);
    attn_mfma<<<dim3(8, 8, 16), 256, 0, stream>>>(qkv, vTb, relB, ctx);
    // Wo + bo -> f32
    gemm_bt<<<256, 256, 0, stream>>>(ctx, wTl + 786432, BO + l*512, gout, nullptr, 8192, 512, 512, 1);
    ln_kernel<<<NTOK, 128, 0, stream>>>(hF, gout, LN1G + l*512, LN1B + l*512, hF, hB);
    // FFN1: relu(h @ w1 + b1) -> bf16   (overwrites vT/relB scratch - OK, dead)
    gemm_bt<<<1024, 256, 0, stream>>>(hB, wTl + 1048576, B1 + l*2048, nullptr, ff, 8192, 2048, 512, 3);
    // FFN2: ff @ w2 + b2 -> f32
    gemm_bt<<<256, 256, 0, stream>>>(ff, wTl + 2097152, B2 + l*512, gout, nullptr, 8192, 512, 2048, 1);
    ln_kernel<<<NTOK, 128, 0, stream>>>(hF, gout, LN2G + l*512, LN2B + l*512, hF, hB);
  }
  ln_kernel<<<NTOK, 128, 0, stream>>>(hF, nullptr, ONG, ONB, hF, hB);
  // head: relu(h @ p1_w + p1_b) -> bf16 [8192][256]
  gemm_bt<<<128, 256, 0, stream>>>(hB, wT + P1T_OFF, P1B, nullptr, hd1, 8192, 256, 512, 3);
  head2_kernel<<<2048, 256, 0, stream>>>(hd1, P2W, P2B, out);
}

// Round 5
// 1406.761 us; speedup vs baseline: 3.3966x; 1.0977x over previous
//
#include <hip/hip_runtime.h>

typedef unsigned short u16;
typedef unsigned int   u32;
typedef short   short8  __attribute__((ext_vector_type(8)));
typedef float   floatx4 __attribute__((ext_vector_type(4)));

#define NTOK 8192
#define SEQ  512
#define NLAYER 6

// ---- workspace layout (bytes) ----
#define OFF_WT   ((size_t)0)          // transposed weights (bf16), 19,005,440 u16
#define OFF_HF   ((size_t)38010880)   // h fp32   [8192][512]
#define OFF_HB   ((size_t)54788096)   // h bf16   [8192][512]
#define OFF_QKV  ((size_t)63176704)   // qkv bf16 [8192][1536] (25.2 MB)
#define OFF_CTX  ((size_t)88342528)   // ctx bf16 [8192][512]
#define OFF_GOUT ((size_t)96731136)   // gout0 fp32 [8192][512]
#define OFF_FF   ((size_t)113508352)  // ff bf16  [8192][2048]  (33.5 MB)
#define OFF_HD1  ((size_t)147062784)  // head1 bf16 [8192][256] (4.2 MB)
// aliases:
//   gout1 (split-K partial, f32 [8192][512] = 16.8 MB) -> qkv region (dead
//     during Wo and FFN2: attn/v_transpose consumed qkv; next QKV write is
//     after LN2 consumed gout1)
//   vT bf16 [128 bh][64][512] (8.4 MB) -> ff region (dead during attn)
//   relB_all bf16 [6][272][64] (209 KB) -> hd1 region (hd1 written only at end)
#define OFF_VT   OFF_FF
#define OFF_RELB OFF_HD1

#define LSTRIDE 3145728   // wT elems per layer: [QT;KT;VT](1536x512), WoT, w1T(2048x512), w2T(512x2048)
#define P1T_OFF 18874368  // p1T [256][512]

__device__ __forceinline__ float b2f(u16 v) { return __uint_as_float(((u32)v) << 16); }
__device__ __forceinline__ float lo16(u32 v) { return __uint_as_float(v << 16); }
__device__ __forceinline__ float hi16(u32 v) { return __uint_as_float(v & 0xffff0000u); }
__device__ __forceinline__ u16 f2b(float f) {
  u32 x = __float_as_uint(f);
  return (u16)((x + 0x7fffu + ((x >> 16) & 1u)) >> 16);
}
__device__ __forceinline__ u32 pack2(float a, float b) {
  return (u32)f2b(a) | ((u32)f2b(b) << 16);
}

typedef __attribute__((address_space(1))) void* gas_t;
typedef __attribute__((address_space(3))) void* las_t;

// ---------------------------------------------------------------------------
// Transpose all f32 weight matrices into wT (bf16 [N][K] for gemm_bt).
// ---------------------------------------------------------------------------
__global__ __launch_bounds__(256) void transpose_all(
    const float* __restrict__ Wq, const float* __restrict__ Wk,
    const float* __restrict__ Wv, const float* __restrict__ Wo,
    const float* __restrict__ w1, const float* __restrict__ w2,
    const float* __restrict__ p1, u16* __restrict__ wT)
{
  __shared__ u16 tile[64][65];
  const int tb = blockIdx.x;
  const float* src; u16* dst; int R, C, tidx;
  if (tb < 4608) {
    const int l = tb / 768, r = tb % 768;
    const size_t lofs = (size_t)l * LSTRIDE;
    if (r < 256) {
      const int m = r >> 6; tidx = r & 63; R = 512; C = 512;
      const float* bases[4] = {Wq, Wk, Wv, Wo};
      src = bases[m] + (size_t)l * 262144;
      dst = wT + lofs + (size_t)m * 262144;
    } else if (r < 512) {
      tidx = r - 256; R = 512; C = 2048;
      src = w1 + (size_t)l * 1048576; dst = wT + lofs + 1048576;
    } else {
      tidx = r - 512; R = 2048; C = 512;
      src = w2 + (size_t)l * 1048576; dst = wT + lofs + 2097152;
    }
  } else {
    tidx = tb - 4608; R = 512; C = 256;
    src = p1; dst = wT + P1T_OFF;
  }
  const int tcn = C >> 6;
  const int tr = tidx / tcn, tc = tidx % tcn;
  const int th = threadIdx.x;
  {
    const int lr = th >> 2, cg = (th & 3) * 16;
    const float* sp = src + (size_t)(tr*64 + lr) * C + tc*64 + cg;
    float4 f0 = *(const float4*)(sp);
    float4 f1 = *(const float4*)(sp + 4);
    float4 f2 = *(const float4*)(sp + 8);
    float4 f3 = *(const float4*)(sp + 12);
    u16* tp = &tile[lr][cg];
    tp[0]=f2b(f0.x); tp[1]=f2b(f0.y); tp[2]=f2b(f0.z); tp[3]=f2b(f0.w);
    tp[4]=f2b(f1.x); tp[5]=f2b(f1.y); tp[6]=f2b(f1.z); tp[7]=f2b(f1.w);
    tp[8]=f2b(f2.x); tp[9]=f2b(f2.y); tp[10]=f2b(f2.z); tp[11]=f2b(f2.w);
    tp[12]=f2b(f3.x); tp[13]=f2b(f3.y); tp[14]=f2b(f3.z); tp[15]=f2b(f3.w);
  }
  __syncthreads();
  {
    const int oc = th >> 2, rg = (th & 3) * 16;
    u32 wds[8];
    #pragma unroll
    for (int i = 0; i < 8; ++i)
      wds[i] = (u32)tile[rg + 2*i][oc] | ((u32)tile[rg + 2*i + 1][oc] << 16);
    u16* dp = dst + (size_t)(tc*64 + oc) * R + tr*64 + rg;
    uint4 o0; o0.x=wds[0]; o0.y=wds[1]; o0.z=wds[2]; o0.w=wds[3];
    uint4 o1; o1.x=wds[4]; o1.y=wds[5]; o1.z=wds[6]; o1.w=wds[7];
    *(uint4*)dp = o0;
    *(uint4*)(dp + 8) = o1;
  }
}

// ---------------------------------------------------------------------------
// h = x @ in_w + in_b + sinusoidal_pe   (K=50, exact f32)
// ---------------------------------------------------------------------------
__global__ __launch_bounds__(128) void input_proj(
    const float* __restrict__ x, const float* __restrict__ w, const float* __restrict__ ib,
    float* __restrict__ hf, u16* __restrict__ hb)
{
  const int row = blockIdx.x, t = threadIdx.x;
  const int s = row & (SEQ - 1);
  __shared__ float xs[50];
  if (t < 50) xs[t] = x[row*50 + t];
  __syncthreads();
  #pragma unroll
  for (int rep = 0; rep < 4; ++rep) {
    const int d = rep*128 + t;
    float acc = ib[d];
    #pragma unroll
    for (int i = 0; i < 50; ++i) acc += xs[i] * w[i*512 + d];
    const int ii = d >> 1;
    const float dv = __expf((float)(2*ii) * -0.017988946f); // -ln(10000)/512
    const float ang = (float)s * dv;
    const float pe = (d & 1) ? cosf(ang) : sinf(ang);
    const float v = acc + pe;
    hf[(size_t)row*512 + d] = v;
    hb[(size_t)row*512 + d] = f2b(v);
  }
}

// ---------------------------------------------------------------------------
// C[M][N] = A[M][K] @ Bt[N][K]^T over k in [z*kLen, (z+1)*kLen)
// z = blockIdx.y. z==0 -> outF0/outB (+bias, relu); z==1 -> outF1 (raw partial)
// ---------------------------------------------------------------------------
__global__ __launch_bounds__(256) void gemm_bt(
    const u16* __restrict__ A, const u16* __restrict__ Bt,
    const float* __restrict__ bias,
    float* __restrict__ outF0, float* __restrict__ outF1, u16* __restrict__ outB,
    const int M, const int N, const int K, const int kLen, const int flags)
{
  __shared__ __align__(16) u16 As[128*32];
  __shared__ __align__(16) u16 Bs[128*32];
  const int nb = N >> 7;
  const int bm = blockIdx.x / nb, bn = blockIdx.x % nb;
  const int z = blockIdx.y;
  const int kOff = z * kLen;
  const int m0 = bm << 7, n0 = bn << 7;
  const int tid = threadIdx.x;
  const int wave = tid >> 6, lane = tid & 63;
  const int wr = (wave >> 1) << 6, wc = (wave & 1) << 6;
  const int lrow = lane & 15, lquad = lane >> 4;

  floatx4 acc[4][4];
  #pragma unroll
  for (int i = 0; i < 4; ++i)
    #pragma unroll
    for (int j = 0; j < 4; ++j) { floatx4 zz = {0.f,0.f,0.f,0.f}; acc[i][j] = zz; }

  const u16* a0p = A  + (size_t)m0 * K + kOff;
  const u16* b0p = Bt + (size_t)n0 * K + kOff;
  const int c0 = tid, c1 = 256 + tid;
  const int ar0 = c0 >> 2, as0 = (c0 & 3) * 8;
  const int ar1 = c1 >> 2, as1 = (c1 & 3) * 8;

  for (int k0 = 0; k0 < kLen; k0 += 32) {
    __builtin_amdgcn_global_load_lds((gas_t)(a0p + (size_t)ar0*K + k0 + as0), (las_t)(&As[c0*8]), 16, 0, 0);
    __builtin_amdgcn_global_load_lds((gas_t)(a0p + (size_t)ar1*K + k0 + as1), (las_t)(&As[c1*8]), 16, 0, 0);
    __builtin_amdgcn_global_load_lds((gas_t)(b0p + (size_t)ar0*K + k0 + as0), (las_t)(&Bs[c0*8]), 16, 0, 0);
    __builtin_amdgcn_global_load_lds((gas_t)(b0p + (size_t)ar1*K + k0 + as1), (las_t)(&Bs[c1*8]), 16, 0, 0);
    __syncthreads();
    short8 af[4], bf[4];
    #pragma unroll
    for (int i = 0; i < 4; ++i) af[i] = *(const short8*)&As[(wr + i*16 + lrow)*32 + lquad*8];
    #pragma unroll
    for (int j = 0; j < 4; ++j) bf[j] = *(const short8*)&Bs[(wc + j*16 + lrow)*32 + lquad*8];
    #pragma unroll
    for (int i = 0; i < 4; ++i)
      #pragma unroll
      for (int j = 0; j < 4; ++j)
        acc[i][j] = __builtin_amdgcn_mfma_f32_16x16x32_bf16(af[i], bf[j], acc[i][j], 0, 0, 0);
    __syncthreads();
  }

  float* outF = (z == 0) ? outF0 : outF1;
  const bool hasb = ((flags & 1) != 0) && (z == 0);
  const bool dorelu = (flags & 2) != 0;
  #pragma unroll
  for (int j = 0; j < 4; ++j) {
    const int col = n0 + wc + j*16 + lrow;
    const float bv = hasb ? bias[col] : 0.f;
    #pragma unroll
    for (int i = 0; i < 4; ++i) {
      const int r0 = m0 + wr + i*16 + lquad*4;
      #pragma unroll
      for (int v = 0; v < 4; ++v) {
        float val = acc[i][j][v] + bv;
        if (dorelu) val = fmaxf(val, 0.f);
        const size_t off = (size_t)(r0 + v) * N + col;
        if (outB) outB[off] = f2b(val);
        else      outF[off] = val;
      }
    }
  }
}

// ---------------------------------------------------------------------------
// V transpose: qkv v-part [b*512+s][1024 + h*64 + d] -> vT[(b*8+h)*64+d][512 s]
// ---------------------------------------------------------------------------
__global__ __launch_bounds__(256) void v_transpose(
    const u16* __restrict__ qkv, u16* __restrict__ vT)
{
  const int kt = blockIdx.x, h = blockIdx.y, b = blockIdx.z;
  __shared__ u16 tile[64*72];
  const int t = threadIdx.x;
  const int row = t >> 2, cg = (t & 3) * 16;
  const u16* sp = qkv + (size_t)(b*512 + kt*64 + row)*1536 + 1024 + h*64 + cg;
  uint4 a0 = *(const uint4*)sp;
  uint4 a1 = *(const uint4*)(sp + 8);
  *(uint4*)&tile[row*72 + cg]     = a0;
  *(uint4*)&tile[row*72 + cg + 8] = a1;
  __syncthreads();
  const int d = row;
  u32 wds[8];
  #pragma unroll
  for (int i = 0; i < 8; ++i)
    wds[i] = (u32)tile[(cg + 2*i)*72 + d] | ((u32)tile[(cg + 2*i + 1)*72 + d] << 16);
  u16* dp = vT + ((size_t)(b*8 + h)*64 + d)*512 + kt*64 + cg;
  uint4 o0; o0.x=wds[0]; o0.y=wds[1]; o0.z=wds[2]; o0.w=wds[3];
  uint4 o1; o1.x=wds[4]; o1.y=wds[5]; o1.z=wds[6]; o1.w=wds[7];
  *(uint4*)dp = o0;
  *(uint4*)(dp + 8) = o1;
}

// ---------------------------------------------------------------------------
// All layers' rel_emb f32 [6][257][64] -> bf16 relB_all [6][272][64]
// ---------------------------------------------------------------------------
__global__ __launch_bounds__(256) void cvt_rel_all(
    const float* __restrict__ rel, u16* __restrict__ relB)
{
  const int i = blockIdx.x*256 + threadIdx.x;
  if (i < 6*257*64) {
    const int l = i / 16448, rem = i % 16448;
    relB[l*17408 + rem] = f2b(rel[i]);
  }
}

// ---------------------------------------------------------------------------
// MFMA flash attention, rel-pos bias, max-free softmax (scores provably small),
// l via ones-MFMA. Block = (qt, h, b); wave w owns q rows [w*16, w*16+16).
// LDS 53 KB -> 3 blocks/CU.
// ---------------------------------------------------------------------------
__global__ __launch_bounds__(256) void attn_mfma(
    const u16* __restrict__ qkv, const u16* __restrict__ vT,
    const u16* __restrict__ relB, u16* __restrict__ ctx)
{
  const int qt = blockIdx.x, h = blockIdx.y, b = blockIdx.z;
  const int t = threadIdx.x, w = t >> 6, lane = t & 63;
  const int lr = lane & 15, quad = lane >> 4;

  __shared__ __align__(16) u16 Ks[64*72];   // K tile, then aliased as P tile
  __shared__ __align__(16) u16 Vs[64*72];
  __shared__ __align__(16) u16 Pr[64*280];  // proj table, rows wave-private

  const size_t token0 = (size_t)b*512 + qt*64;

  // Q A-fragments held in regs: rows w*16+lr, k = quad*8 (+32)
  short8 af0, af1;
  {
    const u16* qp = qkv + (token0 + w*16 + lr)*1536 + h*64 + quad*8;
    af0 = *(const short8*)(qp);
    af1 = *(const short8*)(qp + 32);
  }

  // Pr[q][j] = Q[q] . relB[j]  (each wave: its 16 rows x 272 cols)
  #pragma unroll 4
  for (int nt = 0; nt < 17; ++nt) {
    const u16* rp = relB + (nt*16 + lr)*64 + quad*8;
    short8 rb0 = *(const short8*)(rp);
    short8 rb1 = *(const short8*)(rp + 32);
    floatx4 c = {0.f,0.f,0.f,0.f};
    c = __builtin_amdgcn_mfma_f32_16x16x32_bf16(af0, rb0, c, 0, 0, 0);
    c = __builtin_amdgcn_mfma_f32_16x16x32_bf16(af1, rb1, c, 0, 0, 0);
    #pragma unroll
    for (int r = 0; r < 4; ++r)
      Pr[(w*16 + quad*4 + r)*280 + nt*16 + lr] = f2b(c[r]);
  }

  floatx4 oacc[4];
  floatx4 lacc = {0.f,0.f,0.f,0.f};
  #pragma unroll
  for (int n = 0; n < 4; ++n) { floatx4 zz = {0.f,0.f,0.f,0.f}; oacc[n] = zz; }

  short8 ones;
  #pragma unroll
  for (int i = 0; i < 8; ++i) ones[i] = (short)0x3F80;  // bf16 1.0

  const int srow = t >> 2, scol = (t & 3) * 16;
  const u16* kbase = qkv + (size_t)b*512*1536 + 512 + h*64;
  const u16* vbase = vT + (size_t)(b*8 + h)*64*512;
  const int qg0 = qt*64 + w*16 + quad*4;

  for (int kt = 0; kt < 8; ++kt) {
    __syncthreads();  // prev iter's P/V reads done before overwrite
    { // stage K tile [k][d] and Vt tile [d][k] into padded LDS
      const u16* kp = kbase + (size_t)(kt*64 + srow)*1536 + scol;
      uint4 k0 = *(const uint4*)kp;
      uint4 k1 = *(const uint4*)(kp + 8);
      const u16* vp = vbase + (size_t)srow*512 + kt*64 + scol;
      uint4 v0 = *(const uint4*)vp;
      uint4 v1 = *(const uint4*)(vp + 8);
      *(uint4*)&Ks[srow*72 + scol]     = k0;
      *(uint4*)&Ks[srow*72 + scol + 8] = k1;
      *(uint4*)&Vs[srow*72 + scol]     = v0;
      *(uint4*)&Vs[srow*72 + scol + 8] = v1;
    }
    __syncthreads();

    // S = Q . K^T  (wave's 16 q rows x 64 k cols)
    floatx4 s4[4];
    #pragma unroll
    for (int nt = 0; nt < 4; ++nt) {
      short8 kb0 = *(const short8*)&Ks[(nt*16 + lr)*72 + quad*8];
      short8 kb1 = *(const short8*)&Ks[(nt*16 + lr)*72 + 32 + quad*8];
      floatx4 c = {0.f,0.f,0.f,0.f};
      c = __builtin_amdgcn_mfma_f32_16x16x32_bf16(af0, kb0, c, 0, 0, 0);
      c = __builtin_amdgcn_mfma_f32_16x16x32_bf16(af1, kb1, c, 0, 0, 0);
      s4[nt] = c;
    }
    __syncthreads();  // all waves done reading Ks before P overwrites it

    // P = exp(S/8 + bias); write into Ks region (own rows only)
    const int kpos = kt*64 + lr;
    #pragma unroll
    for (int r = 0; r < 4; ++r) {
      const int qg = qg0 + r;
      const int prrow = (w*16 + quad*4 + r)*280;
      const int psrow = (w*16 + quad*4 + r)*72;
      #pragma unroll
      for (int nt = 0; nt < 4; ++nt) {
        int dd = (kpos + nt*16) - qg;
        dd = dd < -128 ? -128 : (dd > 128 ? 128 : dd);
        const float sc = fmaf(s4[nt][r], 0.125f, b2f(Pr[prrow + dd + 128]));
        Ks[psrow + nt*16 + lr] = f2b(__expf(sc));
      }
    }

    // O += P . V ; l += P . 1  (A-frag rows are wave-private: no barrier)
    short8 pf0 = *(const short8*)&Ks[(w*16 + lr)*72 + quad*8];
    short8 pf1 = *(const short8*)&Ks[(w*16 + lr)*72 + 32 + quad*8];
    lacc = __builtin_amdgcn_mfma_f32_16x16x32_bf16(pf0, ones, lacc, 0, 0, 0);
    lacc = __builtin_amdgcn_mfma_f32_16x16x32_bf16(pf1, ones, lacc, 0, 0, 0);
    #pragma unroll
    for (int nd = 0; nd < 4; ++nd) {
      short8 vb0 = *(const short8*)&Vs[(nd*16 + lr)*72 + quad*8];
      short8 vb1 = *(const short8*)&Vs[(nd*16 + lr)*72 + 32 + quad*8];
      oacc[nd] = __builtin_amdgcn_mfma_f32_16x16x32_bf16(pf0, vb0, oacc[nd], 0, 0, 0);
      oacc[nd] = __builtin_amdgcn_mfma_f32_16x16x32_bf16(pf1, vb1, oacc[nd], 0, 0, 0);
    }
  }

  // epilogue: ctx[token][h*64 + d]; lacc[r] holds row-sum (same in all cols)
  #pragma unroll
  for (int r = 0; r < 4; ++r) {
    const float inv = 1.f / lacc[r];
    u16* cp = ctx + (token0 + w*16 + quad*4 + r)*512 + h*64 + lr;
    #pragma unroll
    for (int nd = 0; nd < 4; ++nd)
      cp[nd*16] = f2b(oacc[nd][r] * inv);
  }
}

// ---------------------------------------------------------------------------
// LayerNorm over D=512: h = LN(res (+ add0) (+ add1)) * g + b -> hf + hb
// ---------------------------------------------------------------------------
__global__ __launch_bounds__(128) void ln_kernel(
    const float* __restrict__ res, const float* __restrict__ add0,
    const float* __restrict__ add1,
    const float* __restrict__ g, const float* __restrict__ be,
    float* __restrict__ hf, u16* __restrict__ hb)
{
  const int row = blockIdx.x, t = threadIdx.x;
  const size_t base = (size_t)row * 512;
  float4 x = *(const float4*)(res + base + t*4);
  if (add0) {
    const float4 a = *(const float4*)(add0 + base + t*4);
    x.x += a.x; x.y += a.y; x.z += a.z; x.w += a.w;
  }
  if (add1) {
    const float4 a = *(const float4*)(add1 + base + t*4);
    x.x += a.x; x.y += a.y; x.z += a.z; x.w += a.w;
  }
  float s = x.x + x.y + x.z + x.w;
  #pragma unroll
  for (int off = 32; off > 0; off >>= 1) s += __shfl_down(s, off);
  __shared__ float red[2];
  const int wv = t >> 6, ln = t & 63;
  if (ln == 0) red[wv] = s;
  __syncthreads();
  const float mean = (red[0] + red[1]) * (1.f/512.f);
  const float dx0 = x.x-mean, dx1 = x.y-mean, dx2 = x.z-mean, dx3 = x.w-mean;
  float vs = dx0*dx0 + dx1*dx1 + dx2*dx2 + dx3*dx3;
  __syncthreads();
  #pragma unroll
  for (int off = 32; off > 0; off >>= 1) vs += __shfl_down(vs, off);
  if (ln == 0) red[wv] = vs;
  __syncthreads();
  const float var = (red[0] + red[1]) * (1.f/512.f);
  const float inv = 1.f / sqrtf(var + 1e-5f);
  const float4 gv = *(const float4*)(g + t*4);
  const float4 bv = *(const float4*)(be + t*4);
  const float y0 = dx0*inv*gv.x + bv.x;
  const float y1 = dx1*inv*gv.y + bv.y;
  const float y2 = dx2*inv*gv.z + bv.z;
  const float y3 = dx3*inv*gv.w + bv.w;
  *(float4*)(hf + base + t*4) = make_float4(y0, y1, y2, y3);
  u32* hp = (u32*)(hb + base + t*4);
  hp[0] = pack2(y0, y1); hp[1] = pack2(y2, y3);
}

// ---------------------------------------------------------------------------
// out[row] = hd1[row][:] . p2_w + p2_b   (256-dot, one wave per row), f32 out
// ---------------------------------------------------------------------------
__global__ __launch_bounds__(256) void head2_kernel(
    const u16* __restrict__ hd1, const float* __restrict__ p2w,
    const float* __restrict__ p2b, float* __restrict__ out)
{
  const int wv = threadIdx.x >> 6, ln = threadIdx.x & 63;
  const int row = blockIdx.x * 4 + wv;
  const u16* hp = hd1 + (size_t)row * 256 + ln*4;
  const u32 h0 = *(const u32*)hp, h1 = *(const u32*)(hp + 2);
  const float4 w = *(const float4*)(p2w + ln*4);
  float acc = lo16(h0)*w.x + hi16(h0)*w.y + lo16(h1)*w.z + hi16(h1)*w.w;
  #pragma unroll
  for (int off = 1; off < 64; off <<= 1) acc += __shfl_xor(acc, off);
  if (ln == 0) out[row] = acc + p2b[0];
}

// ---------------------------------------------------------------------------
extern "C" void kernel_launch(void* const* d_in, const int* in_sizes, int n_in,
                              void* d_out, int out_size, void* d_ws, size_t ws_size,
                              hipStream_t stream) {
  (void)in_sizes; (void)n_in; (void)out_size; (void)ws_size;
  const float* X    = (const float*)d_in[0];
  const float* INW  = (const float*)d_in[1];
  const float* INB  = (const float*)d_in[2];
  const float* WQ   = (const float*)d_in[3];
  const float* WK   = (const float*)d_in[4];
  const float* WV   = (const float*)d_in[5];
  const float* WO   = (const float*)d_in[6];
  const float* BO   = (const float*)d_in[7];
  const float* REL  = (const float*)d_in[8];
  const float* W1   = (const float*)d_in[9];
  const float* B1   = (const float*)d_in[10];
  const float* W2   = (const float*)d_in[11];
  const float* B2   = (const float*)d_in[12];
  const float* LN1G = (const float*)d_in[13];
  const float* LN1B = (const float*)d_in[14];
  const float* LN2G = (const float*)d_in[15];
  const float* LN2B = (const float*)d_in[16];
  const float* ONG  = (const float*)d_in[17];
  const float* ONB  = (const float*)d_in[18];
  const float* P1W  = (const float*)d_in[19];
  const float* P1B  = (const float*)d_in[20];
  const float* P2W  = (const float*)d_in[21];
  const float* P2B  = (const float*)d_in[22];
  float* out = (float*)d_out;

  char* ws = (char*)d_ws;
  u16*   wT    = (u16*)(ws + OFF_WT);
  float* hF    = (float*)(ws + OFF_HF);
  u16*   hB    = (u16*)(ws + OFF_HB);
  u16*   qkv   = (u16*)(ws + OFF_QKV);
  u16*   ctx   = (u16*)(ws + OFF_CTX);
  float* gout0 = (float*)(ws + OFF_GOUT);
  float* gout1 = (float*)(ws + OFF_QKV);   // alias: dead during Wo/FFN2
  u16*   ff    = (u16*)(ws + OFF_FF);
  u16*   hd1   = (u16*)(ws + OFF_HD1);
  u16*   vTb   = (u16*)(ws + OFF_VT);
  u16*   relBa = (u16*)(ws + OFF_RELB);

  transpose_all<<<4640, 256, 0, stream>>>(WQ, WK, WV, WO, W1, W2, P1W, wT);
  cvt_rel_all<<<386, 256, 0, stream>>>(REL, relBa);
  input_proj<<<NTOK, 128, 0, stream>>>(X, INW, INB, hF, hB);

  for (int l = 0; l < NLAYER; ++l) {
    const u16* wTl = wT + (size_t)l * LSTRIDE;
    // QKV fused: [8192,512] @ [512,1536] -> bf16
    gemm_bt<<<dim3(768,1), 256, 0, stream>>>(hB, wTl, nullptr, nullptr, nullptr, qkv,
                                             8192, 1536, 512, 512, 0);
    v_transpose<<<dim3(8, 8, 16), 256, 0, stream>>>(qkv, vTb);
    attn_mfma<<<dim3(8, 8, 16), 256, 0, stream>>>(qkv, vTb, relBa + l*17408, ctx);
    // Wo + bo, split-K=2 -> f32 partials
    gemm_bt<<<dim3(256,2), 256, 0, stream>>>(ctx, wTl + 786432, BO + l*512,
                                             gout0, gout1, nullptr, 8192, 512, 512, 256, 1);
    ln_kernel<<<NTOK, 128, 0, stream>>>(hF, gout0, gout1, LN1G + l*512, LN1B + l*512, hF, hB);
    // FFN1: relu(h @ w1 + b1) -> bf16  (overwrites vT scratch - dead)
    gemm_bt<<<dim3(1024,1), 256, 0, stream>>>(hB, wTl + 1048576, B1 + l*2048,
                                              nullptr, nullptr, ff, 8192, 2048, 512, 512, 3);
    // FFN2: ff @ w2 + b2, split-K=2 -> f32 partials
    gemm_bt<<<dim3(256,2), 256, 0, stream>>>(ff, wTl + 2097152, B2 + l*512,
                                             gout0, gout1, nullptr, 8192, 512, 2048, 1024, 1);
    ln_kernel<<<NTOK, 128, 0, stream>>>(hF, gout0, gout1, LN2G + l*512, LN2B + l*512, hF, hB);
  }
  ln_kernel<<<NTOK, 128, 0, stream>>>(hF, nullptr, nullptr, ONG, ONB, hF, hB);
  // head: relu(h @ p1_w + p1_b) -> bf16 [8192][256]
  gemm_bt<<<dim3(128,1), 256, 0, stream>>>(hB, wT + P1T_OFF, P1B,
                                           nullptr, nullptr, hd1, 8192, 256, 512, 512, 3);
  head2_kernel<<<2048, 256, 0, stream>>>(hd1, P2W, P2B, out);
}

// Round 6
// 1369.914 us; speedup vs baseline: 3.4880x; 1.0269x over previous
//
#include <hip/hip_runtime.h>

typedef unsigned short u16;
typedef unsigned int   u32;
typedef short   short8  __attribute__((ext_vector_type(8)));
typedef float   floatx4 __attribute__((ext_vector_type(4)));

#define NTOK 8192
#define SEQ  512
#define NLAYER 6

// ---- workspace layout (bytes) ----
#define OFF_WT   ((size_t)0)          // transposed weights (bf16), 19,005,440 u16
#define OFF_HF   ((size_t)38010880)   // h fp32   [8192][512]
#define OFF_HB   ((size_t)54788096)   // h bf16   [8192][512]
#define OFF_QKV  ((size_t)63176704)   // qkv bf16 [8192][1536] (25.2 MB)
#define OFF_CTX  ((size_t)88342528)   // ctx bf16 [8192][512]
#define OFF_GOUT ((size_t)96731136)   // gout0 fp32 [8192][512]
#define OFF_FF   ((size_t)113508352)  // ff bf16  [8192][2048]  (33.5 MB)
#define OFF_HD1  ((size_t)147062784)  // head1 bf16 [8192][256] (4.2 MB)
// aliases:
//   gout1 (split-K partial, f32 [8192][512]) -> qkv region (dead during Wo/FFN2)
//   vT bf16 [128 bh][64][512] (8.4 MB) -> ff region (dead during attn)
//   relB_all bf16 [6][272][64] (209 KB) -> hd1 region (hd1 written only at end)
#define OFF_VT   OFF_FF
#define OFF_RELB OFF_HD1

#define LSTRIDE 3145728   // wT elems per layer: [QT;KT;VT](1536x512), WoT, w1T(2048x512), w2T(512x2048)
#define P1T_OFF 18874368  // p1T [256][512]

__device__ __forceinline__ float b2f(u16 v) { return __uint_as_float(((u32)v) << 16); }
__device__ __forceinline__ float lo16(u32 v) { return __uint_as_float(v << 16); }
__device__ __forceinline__ float hi16(u32 v) { return __uint_as_float(v & 0xffff0000u); }
__device__ __forceinline__ u16 f2b(float f) {
  u32 x = __float_as_uint(f);
  return (u16)((x + 0x7fffu + ((x >> 16) & 1u)) >> 16);
}
__device__ __forceinline__ u32 pack2(float a, float b) {
  return (u32)f2b(a) | ((u32)f2b(b) << 16);
}

typedef __attribute__((address_space(1))) void* gas_t;
typedef __attribute__((address_space(3))) void* las_t;

// ---------------------------------------------------------------------------
// Transpose all f32 weight matrices into wT (bf16 [N][K] for gemm_bt).
// ---------------------------------------------------------------------------
__global__ __launch_bounds__(256) void transpose_all(
    const float* __restrict__ Wq, const float* __restrict__ Wk,
    const float* __restrict__ Wv, const float* __restrict__ Wo,
    const float* __restrict__ w1, const float* __restrict__ w2,
    const float* __restrict__ p1, u16* __restrict__ wT)
{
  __shared__ u16 tile[64][65];
  const int tb = blockIdx.x;
  const float* src; u16* dst; int R, C, tidx;
  if (tb < 4608) {
    const int l = tb / 768, r = tb % 768;
    const size_t lofs = (size_t)l * LSTRIDE;
    if (r < 256) {
      const int m = r >> 6; tidx = r & 63; R = 512; C = 512;
      const float* bases[4] = {Wq, Wk, Wv, Wo};
      src = bases[m] + (size_t)l * 262144;
      dst = wT + lofs + (size_t)m * 262144;
    } else if (r < 512) {
      tidx = r - 256; R = 512; C = 2048;
      src = w1 + (size_t)l * 1048576; dst = wT + lofs + 1048576;
    } else {
      tidx = r - 512; R = 2048; C = 512;
      src = w2 + (size_t)l * 1048576; dst = wT + lofs + 2097152;
    }
  } else {
    tidx = tb - 4608; R = 512; C = 256;
    src = p1; dst = wT + P1T_OFF;
  }
  const int tcn = C >> 6;
  const int tr = tidx / tcn, tc = tidx % tcn;
  const int th = threadIdx.x;
  {
    const int lr = th >> 2, cg = (th & 3) * 16;
    const float* sp = src + (size_t)(tr*64 + lr) * C + tc*64 + cg;
    float4 f0 = *(const float4*)(sp);
    float4 f1 = *(const float4*)(sp + 4);
    float4 f2 = *(const float4*)(sp + 8);
    float4 f3 = *(const float4*)(sp + 12);
    u16* tp = &tile[lr][cg];
    tp[0]=f2b(f0.x); tp[1]=f2b(f0.y); tp[2]=f2b(f0.z); tp[3]=f2b(f0.w);
    tp[4]=f2b(f1.x); tp[5]=f2b(f1.y); tp[6]=f2b(f1.z); tp[7]=f2b(f1.w);
    tp[8]=f2b(f2.x); tp[9]=f2b(f2.y); tp[10]=f2b(f2.z); tp[11]=f2b(f2.w);
    tp[12]=f2b(f3.x); tp[13]=f2b(f3.y); tp[14]=f2b(f3.z); tp[15]=f2b(f3.w);
  }
  __syncthreads();
  {
    const int oc = th >> 2, rg = (th & 3) * 16;
    u32 wds[8];
    #pragma unroll
    for (int i = 0; i < 8; ++i)
      wds[i] = (u32)tile[rg + 2*i][oc] | ((u32)tile[rg + 2*i + 1][oc] << 16);
    u16* dp = dst + (size_t)(tc*64 + oc) * R + tr*64 + rg;
    uint4 o0; o0.x=wds[0]; o0.y=wds[1]; o0.z=wds[2]; o0.w=wds[3];
    uint4 o1; o1.x=wds[4]; o1.y=wds[5]; o1.z=wds[6]; o1.w=wds[7];
    *(uint4*)dp = o0;
    *(uint4*)(dp + 8) = o1;
  }
}

// ---------------------------------------------------------------------------
// h = x @ in_w + in_b + sinusoidal_pe   (K=50, exact f32)
// ---------------------------------------------------------------------------
__global__ __launch_bounds__(128) void input_proj(
    const float* __restrict__ x, const float* __restrict__ w, const float* __restrict__ ib,
    float* __restrict__ hf, u16* __restrict__ hb)
{
  const int row = blockIdx.x, t = threadIdx.x;
  const int s = row & (SEQ - 1);
  __shared__ float xs[50];
  if (t < 50) xs[t] = x[row*50 + t];
  __syncthreads();
  #pragma unroll
  for (int rep = 0; rep < 4; ++rep) {
    const int d = rep*128 + t;
    float acc = ib[d];
    #pragma unroll
    for (int i = 0; i < 50; ++i) acc += xs[i] * w[i*512 + d];
    const int ii = d >> 1;
    const float dv = __expf((float)(2*ii) * -0.017988946f); // -ln(10000)/512
    const float ang = (float)s * dv;
    const float pe = (d & 1) ? cosf(ang) : sinf(ang);
    const float v = acc + pe;
    hf[(size_t)row*512 + d] = v;
    hb[(size_t)row*512 + d] = f2b(v);
  }
}

// ---------------------------------------------------------------------------
// C[M][N] = A[M][K] @ Bt[N][K]^T over k in [z*kLen, (z+1)*kLen)
// z = blockIdx.y. z==0 gets +bias; relu per flags bit1.
// flags bit2: blocks with n0>=1024 write V directly in vT-transposed layout.
// ---------------------------------------------------------------------------
__global__ __launch_bounds__(256) void gemm_bt(
    const u16* __restrict__ A, const u16* __restrict__ Bt,
    const float* __restrict__ bias,
    float* __restrict__ outF0, float* __restrict__ outF1, u16* __restrict__ outB,
    u16* __restrict__ vTout,
    const int M, const int N, const int K, const int kLen, const int flags)
{
  __shared__ __align__(16) u16 As[128*32];
  __shared__ __align__(16) u16 Bs[128*32];
  const int nb = N >> 7;
  const int bm = blockIdx.x / nb, bn = blockIdx.x % nb;
  const int z = blockIdx.y;
  const int kOff = z * kLen;
  const int m0 = bm << 7, n0 = bn << 7;
  const int tid = threadIdx.x;
  const int wave = tid >> 6, lane = tid & 63;
  const int wr = (wave >> 1) << 6, wc = (wave & 1) << 6;
  const int lrow = lane & 15, lquad = lane >> 4;

  floatx4 acc[4][4];
  #pragma unroll
  for (int i = 0; i < 4; ++i)
    #pragma unroll
    for (int j = 0; j < 4; ++j) { floatx4 zz = {0.f,0.f,0.f,0.f}; acc[i][j] = zz; }

  const u16* a0p = A  + (size_t)m0 * K + kOff;
  const u16* b0p = Bt + (size_t)n0 * K + kOff;
  const int c0 = tid, c1 = 256 + tid;
  const int ar0 = c0 >> 2, as0 = (c0 & 3) * 8;
  const int ar1 = c1 >> 2, as1 = (c1 & 3) * 8;

  for (int k0 = 0; k0 < kLen; k0 += 32) {
    __builtin_amdgcn_global_load_lds((gas_t)(a0p + (size_t)ar0*K + k0 + as0), (las_t)(&As[c0*8]), 16, 0, 0);
    __builtin_amdgcn_global_load_lds((gas_t)(a0p + (size_t)ar1*K + k0 + as1), (las_t)(&As[c1*8]), 16, 0, 0);
    __builtin_amdgcn_global_load_lds((gas_t)(b0p + (size_t)ar0*K + k0 + as0), (las_t)(&Bs[c0*8]), 16, 0, 0);
    __builtin_amdgcn_global_load_lds((gas_t)(b0p + (size_t)ar1*K + k0 + as1), (las_t)(&Bs[c1*8]), 16, 0, 0);
    __syncthreads();
    short8 af[4], bf[4];
    #pragma unroll
    for (int i = 0; i < 4; ++i) af[i] = *(const short8*)&As[(wr + i*16 + lrow)*32 + lquad*8];
    #pragma unroll
    for (int j = 0; j < 4; ++j) bf[j] = *(const short8*)&Bs[(wc + j*16 + lrow)*32 + lquad*8];
    #pragma unroll
    for (int i = 0; i < 4; ++i)
      #pragma unroll
      for (int j = 0; j < 4; ++j)
        acc[i][j] = __builtin_amdgcn_mfma_f32_16x16x32_bf16(af[i], bf[j], acc[i][j], 0, 0, 0);
    __syncthreads();
  }

  if ((flags & 4) && n0 >= 1024) {
    // V block of QKV: write directly into vT[(b*8+h)*64+d][s] (bf16)
    #pragma unroll
    for (int j = 0; j < 4; ++j) {
      const int cm = (n0 - 1024) + wc + j*16 + lrow;
      const int hh = cm >> 6, d = cm & 63;
      #pragma unroll
      for (int i = 0; i < 4; ++i) {
        const int r0 = m0 + wr + i*16 + lquad*4;
        const int bb = r0 >> 9, s = r0 & 511;
        uint2 o;
        o.x = pack2(acc[i][j][0], acc[i][j][1]);
        o.y = pack2(acc[i][j][2], acc[i][j][3]);
        *(uint2*)(vTout + ((size_t)(bb*8 + hh)*64 + d)*512 + s) = o;
      }
    }
    return;
  }

  float* outF = (z == 0) ? outF0 : outF1;
  const bool hasb = ((flags & 1) != 0) && (z == 0);
  const bool dorelu = (flags & 2) != 0;
  #pragma unroll
  for (int j = 0; j < 4; ++j) {
    const int col = n0 + wc + j*16 + lrow;
    const float bv = hasb ? bias[col] : 0.f;
    #pragma unroll
    for (int i = 0; i < 4; ++i) {
      const int r0 = m0 + wr + i*16 + lquad*4;
      #pragma unroll
      for (int v = 0; v < 4; ++v) {
        float val = acc[i][j][v] + bv;
        if (dorelu) val = fmaxf(val, 0.f);
        const size_t off = (size_t)(r0 + v) * N + col;
        if (outB) outB[off] = f2b(val);
        else      outF[off] = val;
      }
    }
  }
}

// ---------------------------------------------------------------------------
// All layers' rel_emb f32 [6][257][64] -> bf16 relB_all [6][272][64]
// ---------------------------------------------------------------------------
__global__ __launch_bounds__(256) void cvt_rel_all(
    const float* __restrict__ rel, u16* __restrict__ relB)
{
  const int i = blockIdx.x*256 + threadIdx.x;
  if (i < 6*257*64) {
    const int l = i / 16448, rem = i % 16448;
    relB[l*17408 + rem] = f2b(rel[i]);
  }
}

// ---------------------------------------------------------------------------
// MFMA flash attention, rel-pos bias, max-free softmax, l via ones-MFMA.
// Flat grid 1024 with XCD-aware swizzle: id = qt*128 + (bh&15)*8 + bh/16
// -> all 8 qt-blocks of one (b,h) share id%8 (same XCD under round-robin),
// so K/V L2 lines are fetched once per XCD, not 8 times chip-wide.
// ---------------------------------------------------------------------------
__global__ __launch_bounds__(256) void attn_mfma(
    const u16* __restrict__ qkv, const u16* __restrict__ vT,
    const u16* __restrict__ relB, u16* __restrict__ ctx)
{
  const int id = blockIdx.x;
  const int xcd = id & 7, g = (id >> 3) & 15, qt = id >> 7;
  const int bh = xcd*16 + g;
  const int b = bh >> 3, h = bh & 7;
  const int t = threadIdx.x, w = t >> 6, lane = t & 63;
  const int lr = lane & 15, quad = lane >> 4;

  __shared__ __align__(16) u16 Ks[64*72];   // K tile, then aliased as P tile
  __shared__ __align__(16) u16 Vs[64*72];
  __shared__ __align__(16) u16 Pr[64*280];  // proj table, rows wave-private

  const size_t token0 = (size_t)b*512 + qt*64;

  // Q A-fragments held in regs: rows w*16+lr, k = quad*8 (+32)
  short8 af0, af1;
  {
    const u16* qp = qkv + (token0 + w*16 + lr)*1536 + h*64 + quad*8;
    af0 = *(const short8*)(qp);
    af1 = *(const short8*)(qp + 32);
  }

  // Pr[q][j] = Q[q] . relB[j]  (each wave: its 16 rows x 272 cols)
  #pragma unroll 4
  for (int nt = 0; nt < 17; ++nt) {
    const u16* rp = relB + (nt*16 + lr)*64 + quad*8;
    short8 rb0 = *(const short8*)(rp);
    short8 rb1 = *(const short8*)(rp + 32);
    floatx4 c = {0.f,0.f,0.f,0.f};
    c = __builtin_amdgcn_mfma_f32_16x16x32_bf16(af0, rb0, c, 0, 0, 0);
    c = __builtin_amdgcn_mfma_f32_16x16x32_bf16(af1, rb1, c, 0, 0, 0);
    #pragma unroll
    for (int r = 0; r < 4; ++r)
      Pr[(w*16 + quad*4 + r)*280 + nt*16 + lr] = f2b(c[r]);
  }

  floatx4 oacc[4];
  floatx4 lacc = {0.f,0.f,0.f,0.f};
  #pragma unroll
  for (int n = 0; n < 4; ++n) { floatx4 zz = {0.f,0.f,0.f,0.f}; oacc[n] = zz; }

  short8 ones;
  #pragma unroll
  for (int i = 0; i < 8; ++i) ones[i] = (short)0x3F80;  // bf16 1.0

  const int srow = t >> 2, scol = (t & 3) * 16;
  const u16* kbase = qkv + (size_t)b*512*1536 + 512 + h*64;
  const u16* vbase = vT + (size_t)(b*8 + h)*64*512;
  const int qg0 = qt*64 + w*16 + quad*4;

  for (int kt = 0; kt < 8; ++kt) {
    __syncthreads();  // prev iter's P/V reads done before overwrite
    { // stage K tile [k][d] and Vt tile [d][k] into padded LDS
      const u16* kp = kbase + (size_t)(kt*64 + srow)*1536 + scol;
      uint4 k0 = *(const uint4*)kp;
      uint4 k1 = *(const uint4*)(kp + 8);
      const u16* vp = vbase + (size_t)srow*512 + kt*64 + scol;
      uint4 v0 = *(const uint4*)vp;
      uint4 v1 = *(const uint4*)(vp + 8);
      *(uint4*)&Ks[srow*72 + scol]     = k0;
      *(uint4*)&Ks[srow*72 + scol + 8] = k1;
      *(uint4*)&Vs[srow*72 + scol]     = v0;
      *(uint4*)&Vs[srow*72 + scol + 8] = v1;
    }
    __syncthreads();

    // S = Q . K^T  (wave's 16 q rows x 64 k cols)
    floatx4 s4[4];
    #pragma unroll
    for (int nt = 0; nt < 4; ++nt) {
      short8 kb0 = *(const short8*)&Ks[(nt*16 + lr)*72 + quad*8];
      short8 kb1 = *(const short8*)&Ks[(nt*16 + lr)*72 + 32 + quad*8];
      floatx4 c = {0.f,0.f,0.f,0.f};
      c = __builtin_amdgcn_mfma_f32_16x16x32_bf16(af0, kb0, c, 0, 0, 0);
      c = __builtin_amdgcn_mfma_f32_16x16x32_bf16(af1, kb1, c, 0, 0, 0);
      s4[nt] = c;
    }
    __syncthreads();  // all waves done reading Ks before P overwrites it

    // P = exp(S/8 + bias); write into Ks region (own rows only)
    const int kpos = kt*64 + lr;
    #pragma unroll
    for (int r = 0; r < 4; ++r) {
      const int qg = qg0 + r;
      const int prrow = (w*16 + quad*4 + r)*280;
      const int psrow = (w*16 + quad*4 + r)*72;
      #pragma unroll
      for (int nt = 0; nt < 4; ++nt) {
        int dd = (kpos + nt*16) - qg;
        dd = dd < -128 ? -128 : (dd > 128 ? 128 : dd);
        const float sc = fmaf(s4[nt][r], 0.125f, b2f(Pr[prrow + dd + 128]));
        Ks[psrow + nt*16 + lr] = f2b(__expf(sc));
      }
    }

    // O += P . V ; l += P . 1  (A-frag rows are wave-private: no barrier)
    short8 pf0 = *(const short8*)&Ks[(w*16 + lr)*72 + quad*8];
    short8 pf1 = *(const short8*)&Ks[(w*16 + lr)*72 + 32 + quad*8];
    lacc = __builtin_amdgcn_mfma_f32_16x16x32_bf16(pf0, ones, lacc, 0, 0, 0);
    lacc = __builtin_amdgcn_mfma_f32_16x16x32_bf16(pf1, ones, lacc, 0, 0, 0);
    #pragma unroll
    for (int nd = 0; nd < 4; ++nd) {
      short8 vb0 = *(const short8*)&Vs[(nd*16 + lr)*72 + quad*8];
      short8 vb1 = *(const short8*)&Vs[(nd*16 + lr)*72 + 32 + quad*8];
      oacc[nd] = __builtin_amdgcn_mfma_f32_16x16x32_bf16(pf0, vb0, oacc[nd], 0, 0, 0);
      oacc[nd] = __builtin_amdgcn_mfma_f32_16x16x32_bf16(pf1, vb1, oacc[nd], 0, 0, 0);
    }
  }

  // epilogue: ctx[token][h*64 + d]; lacc[r] holds row-sum (same in all cols)
  #pragma unroll
  for (int r = 0; r < 4; ++r) {
    const float inv = 1.f / lacc[r];
    u16* cp = ctx + (token0 + w*16 + quad*4 + r)*512 + h*64 + lr;
    #pragma unroll
    for (int nd = 0; nd < 4; ++nd)
      cp[nd*16] = f2b(oacc[nd][r] * inv);
  }
}

// ---------------------------------------------------------------------------
// LayerNorm over D=512: h = LN(res (+ add0) (+ add1)) * g + b -> hf + hb
// ---------------------------------------------------------------------------
__global__ __launch_bounds__(128) void ln_kernel(
    const float* __restrict__ res, const float* __restrict__ add0,
    const float* __restrict__ add1,
    const float* __restrict__ g, const float* __restrict__ be,
    float* __restrict__ hf, u16* __restrict__ hb)
{
  const int row = blockIdx.x, t = threadIdx.x;
  const size_t base = (size_t)row * 512;
  float4 x = *(const float4*)(res + base + t*4);
  if (add0) {
    const float4 a = *(const float4*)(add0 + base + t*4);
    x.x += a.x; x.y += a.y; x.z += a.z; x.w += a.w;
  }
  if (add1) {
    const float4 a = *(const float4*)(add1 + base + t*4);
    x.x += a.x; x.y += a.y; x.z += a.z; x.w += a.w;
  }
  float s = x.x + x.y + x.z + x.w;
  #pragma unroll
  for (int off = 32; off > 0; off >>= 1) s += __shfl_down(s, off);
  __shared__ float red[2];
  const int wv = t >> 6, ln = t & 63;
  if (ln == 0) red[wv] = s;
  __syncthreads();
  const float mean = (red[0] + red[1]) * (1.f/512.f);
  const float dx0 = x.x-mean, dx1 = x.y-mean, dx2 = x.z-mean, dx3 = x.w-mean;
  float vs = dx0*dx0 + dx1*dx1 + dx2*dx2 + dx3*dx3;
  __syncthreads();
  #pragma unroll
  for (int off = 32; off > 0; off >>= 1) vs += __shfl_down(vs, off);
  if (ln == 0) red[wv] = vs;
  __syncthreads();
  const float var = (red[0] + red[1]) * (1.f/512.f);
  const float inv = 1.f / sqrtf(var + 1e-5f);
  const float4 gv = *(const float4*)(g + t*4);
  const float4 bv = *(const float4*)(be + t*4);
  const float y0 = dx0*inv*gv.x + bv.x;
  const float y1 = dx1*inv*gv.y + bv.y;
  const float y2 = dx2*inv*gv.z + bv.z;
  const float y3 = dx3*inv*gv.w + bv.w;
  *(float4*)(hf + base + t*4) = make_float4(y0, y1, y2, y3);
  u32* hp = (u32*)(hb + base + t*4);
  hp[0] = pack2(y0, y1); hp[1] = pack2(y2, y3);
}

// ---------------------------------------------------------------------------
// out[row] = hd1[row][:] . p2_w + p2_b   (256-dot, one wave per row), f32 out
// ---------------------------------------------------------------------------
__global__ __launch_bounds__(256) void head2_kernel(
    const u16* __restrict__ hd1, const float* __restrict__ p2w,
    const float* __restrict__ p2b, float* __restrict__ out)
{
  const int wv = threadIdx.x >> 6, ln = threadIdx.x & 63;
  const int row = blockIdx.x * 4 + wv;
  const u16* hp = hd1 + (size_t)row * 256 + ln*4;
  const u32 h0 = *(const u32*)hp, h1 = *(const u32*)(hp + 2);
  const float4 w = *(const float4*)(p2w + ln*4);
  float acc = lo16(h0)*w.x + hi16(h0)*w.y + lo16(h1)*w.z + hi16(h1)*w.w;
  #pragma unroll
  for (int off = 1; off < 64; off <<= 1) acc += __shfl_xor(acc, off);
  if (ln == 0) out[row] = acc + p2b[0];
}

// ---------------------------------------------------------------------------
extern "C" void kernel_launch(void* const* d_in, const int* in_sizes, int n_in,
                              void* d_out, int out_size, void* d_ws, size_t ws_size,
                              hipStream_t stream) {
  (void)in_sizes; (void)n_in; (void)out_size; (void)ws_size;
  const float* X    = (const float*)d_in[0];
  const float* INW  = (const float*)d_in[1];
  const float* INB  = (const float*)d_in[2];
  const float* WQ   = (const float*)d_in[3];
  const float* WK   = (const float*)d_in[4];
  const float* WV   = (const float*)d_in[5];
  const float* WO   = (const float*)d_in[6];
  const float* BO   = (const float*)d_in[7];
  const float* REL  = (const float*)d_in[8];
  const float* W1   = (const float*)d_in[9];
  const float* B1   = (const float*)d_in[10];
  const float* W2   = (const float*)d_in[11];
  const float* B2   = (const float*)d_in[12];
  const float* LN1G = (const float*)d_in[13];
  const float* LN1B = (const float*)d_in[14];
  const float* LN2G = (const float*)d_in[15];
  const float* LN2B = (const float*)d_in[16];
  const float* ONG  = (const float*)d_in[17];
  const float* ONB  = (const float*)d_in[18];
  const float* P1W  = (const float*)d_in[19];
  const float* P1B  = (const float*)d_in[20];
  const float* P2W  = (const float*)d_in[21];
  const float* P2B  = (const float*)d_in[22];
  float* out = (float*)d_out;

  char* ws = (char*)d_ws;
  u16*   wT    = (u16*)(ws + OFF_WT);
  float* hF    = (float*)(ws + OFF_HF);
  u16*   hB    = (u16*)(ws + OFF_HB);
  u16*   qkv   = (u16*)(ws + OFF_QKV);
  u16*   ctx   = (u16*)(ws + OFF_CTX);
  float* gout0 = (float*)(ws + OFF_GOUT);
  float* gout1 = (float*)(ws + OFF_QKV);   // alias: dead during Wo/FFN2
  u16*   ff    = (u16*)(ws + OFF_FF);
  u16*   hd1   = (u16*)(ws + OFF_HD1);
  u16*   vTb   = (u16*)(ws + OFF_VT);
  u16*   relBa = (u16*)(ws + OFF_RELB);

  transpose_all<<<4640, 256, 0, stream>>>(WQ, WK, WV, WO, W1, W2, P1W, wT);
  cvt_rel_all<<<386, 256, 0, stream>>>(REL, relBa);
  input_proj<<<NTOK, 128, 0, stream>>>(X, INW, INB, hF, hB);

  for (int l = 0; l < NLAYER; ++l) {
    const u16* wTl = wT + (size_t)l * LSTRIDE;
    // QKV fused: [8192,512] @ [512,1536]; Q,K -> qkv bf16, V -> vT transposed
    gemm_bt<<<dim3(768,1), 256, 0, stream>>>(hB, wTl, nullptr, nullptr, nullptr, qkv, vTb,
                                             8192, 1536, 512, 512, 4);
    attn_mfma<<<1024, 256, 0, stream>>>(qkv, vTb, relBa + l*17408, ctx);
    // Wo + bo, split-K=2 -> f32 partials
    gemm_bt<<<dim3(256,2), 256, 0, stream>>>(ctx, wTl + 786432, BO + l*512,
                                             gout0, gout1, nullptr, nullptr,
                                             8192, 512, 512, 256, 1);
    ln_kernel<<<NTOK, 128, 0, stream>>>(hF, gout0, gout1, LN1G + l*512, LN1B + l*512, hF, hB);
    // FFN1: relu(h @ w1 + b1) -> bf16  (overwrites vT scratch - dead)
    gemm_bt<<<dim3(1024,1), 256, 0, stream>>>(hB, wTl + 1048576, B1 + l*2048,
                                              nullptr, nullptr, ff, nullptr,
                                              8192, 2048, 512, 512, 3);
    // FFN2: ff @ w2 + b2, split-K=2 -> f32 partials
    gemm_bt<<<dim3(256,2), 256, 0, stream>>>(ff, wTl + 2097152, B2 + l*512,
                                             gout0, gout1, nullptr, nullptr,
                                             8192, 512, 2048, 1024, 1);
    ln_kernel<<<NTOK, 128, 0, stream>>>(hF, gout0, gout1, LN2G + l*512, LN2B + l*512, hF, hB);
  }
  ln_kernel<<<NTOK, 128, 0, stream>>>(hF, nullptr, nullptr, ONG, ONB, hF, hB);
  // head: relu(h @ p1_w + p1_b) -> bf16 [8192][256]
  gemm_bt<<<dim3(128,1), 256, 0, stream>>>(hB, wT + P1T_OFF, P1B,
                                           nullptr, nullptr, hd1, nullptr,
                                           8192, 256, 512, 512, 3);
  head2_kernel<<<2048, 256, 0, stream>>>(hd1, P2W, P2B, out);
}